// Round 2
// baseline (3994.661 us; speedup 1.0000x reference)
//
#include <hip/hip_runtime.h>
#include <hip/hip_bf16.h>
#include <stdint.h>

// ---------------- geometry ----------------
#define BB   8
#define TT   2048
#define DD   768
#define HH   6
#define DKd  128
#define DVd  256
#define MM   (BB*TT)      // 16384 rows
#define K1   768
#define K2   1536

typedef __bf16 bf16x8 __attribute__((ext_vector_type(8)));
typedef float  f32x4  __attribute__((ext_vector_type(4)));

__device__ __forceinline__ float sigm(float x) { return 1.f / (1.f + __expf(-x)); }

// ---------------- f32 -> split-bf16 conversions ----------------
// Logical A' = [Ahi | Ahi | Alo] (3K blocks), stored compact as [Ahi | Alo] (2K);
// GEMM staging maps logical k-block -> stored block. Weights Bt stored full 3K:
// [Bhi | Blo | Bhi] so A'.B'^T = Ahi.Bhi + Ahi.Blo + Alo.Bhi (~fp32 accuracy).

__global__ void convert_x_kernel(const float* __restrict__ x, __bf16* __restrict__ Xs) {
  int idx = blockIdx.x * 256 + threadIdx.x;
  if (idx >= MM * DD) return;
  int m = idx / DD, c = idx - m * DD;
  float v = x[idx];
  __bf16 h = (__bf16)v;
  __bf16 l = (__bf16)(v - (float)h);
  size_t base = (size_t)m * (2 * K1) + c;
  Xs[base] = h; Xs[base + K1] = l;
}

// W [K,N] f32 row-major -> Wt [N, 3K] bf16, k-blocks [hi | lo | hi]
__global__ void convert_w_kernel(const float* __restrict__ W, __bf16* __restrict__ Wt,
                                 int K, int N) {
  int idx = blockIdx.x * 256 + threadIdx.x;
  if (idx >= N * 3 * K) return;
  int n = idx / (3 * K), kk = idx - n * (3 * K);
  int blk = kk / K, k = kk - blk * K;
  float v = W[(size_t)k * N + n];
  __bf16 h = (__bf16)v;
  Wt[idx] = (blk == 1) ? (__bf16)(v - (float)h) : h;
}

// ---------------- bf16 MFMA GEMM: C[M,N] = A'[M,3K] * Bt[N,3K]^T ----------------
// A stored compact [M, 2K] = [hi|lo]; logical blocks [hi|hi|lo] via kc mapping.
// m97 structure: 128x128 tile, 4 waves (2x2), BK=32, global_load_lds width 16.
template <typename OutT>
__global__ __launch_bounds__(256) void gemm_split(
    const __bf16* __restrict__ A, const __bf16* __restrict__ Bt,
    OutT* __restrict__ C, int N, int Khi)
{
  __shared__ __bf16 Als[128 * 32];
  __shared__ __bf16 Bls[128 * 32];
  const int LDA = 2 * Khi, Klog = 3 * Khi;
  const int tid = threadIdx.x;
  const int lane = tid & 63, w = tid >> 6;
  const int wr = w >> 1, wc = w & 1;
  const int bm = blockIdx.x, bn = blockIdx.y;
  f32x4 acc[4][4] = {};
  const __bf16* Ab = A + (size_t)bm * 128 * LDA;
  const __bf16* Bb = Bt + (size_t)bn * 128 * Klog;
  // staging: chunk c = p*256 + tid ; row = c/4 , col = (c%4)*8 elems
  const int r0 = tid >> 2, co0 = (tid & 3) * 8;
  const int r1 = (256 + tid) >> 2, co1 = ((256 + tid) & 3) * 8;
  for (int k0 = 0; k0 < Klog; k0 += 32) {
    const int kc = (k0 < Khi) ? k0 : k0 - Khi;   // [hi|hi|lo] -> [hi|lo]
    __syncthreads();
    __builtin_amdgcn_global_load_lds(
        (const __attribute__((address_space(1))) void*)(Ab + (size_t)r0 * LDA + kc + co0),
        (__attribute__((address_space(3))) void*)(Als + (w * 64) * 8), 16, 0, 0);
    __builtin_amdgcn_global_load_lds(
        (const __attribute__((address_space(1))) void*)(Ab + (size_t)r1 * LDA + kc + co1),
        (__attribute__((address_space(3))) void*)(Als + (256 + w * 64) * 8), 16, 0, 0);
    __builtin_amdgcn_global_load_lds(
        (const __attribute__((address_space(1))) void*)(Bb + (size_t)r0 * Klog + k0 + co0),
        (__attribute__((address_space(3))) void*)(Bls + (w * 64) * 8), 16, 0, 0);
    __builtin_amdgcn_global_load_lds(
        (const __attribute__((address_space(1))) void*)(Bb + (size_t)r1 * Klog + k0 + co1),
        (__attribute__((address_space(3))) void*)(Bls + (256 + w * 64) * 8), 16, 0, 0);
    __syncthreads();   // vmcnt(0) drain before barrier
    bf16x8 af[4], bfr[4];
    const int rb = wr * 64 + (lane & 15);
    const int kb = (lane >> 4) * 8;
#pragma unroll
    for (int i = 0; i < 4; ++i) af[i] = *(const bf16x8*)(Als + (rb + i * 16) * 32 + kb);
    const int cb = wc * 64 + (lane & 15);
#pragma unroll
    for (int i = 0; i < 4; ++i) bfr[i] = *(const bf16x8*)(Bls + (cb + i * 16) * 32 + kb);
#pragma unroll
    for (int mi = 0; mi < 4; ++mi)
#pragma unroll
      for (int ni = 0; ni < 4; ++ni)
        acc[mi][ni] = __builtin_amdgcn_mfma_f32_16x16x32_bf16(af[mi], bfr[ni], acc[mi][ni], 0, 0, 0);
  }
  // C/D layout: col = lane&15, row = (lane>>4)*4 + reg  (guide m89/m91)
  const int row0 = bm * 128 + wr * 64;
  const int col0 = bn * 128 + wc * 64 + (lane & 15);
  const int rsub = (lane >> 4) * 4;
#pragma unroll
  for (int mi = 0; mi < 4; ++mi)
#pragma unroll
    for (int ni = 0; ni < 4; ++ni)
#pragma unroll
      for (int r = 0; r < 4; ++r) {
        int row = row0 + mi * 16 + rsub + r;
        C[(size_t)row * N + col0 + ni * 16] = (OutT)acc[mi][ni][r];
      }
}

// ---------------- g / beta projections (N=6 each, direct fp32) ----------------
__global__ void gb_kernel(const float* __restrict__ x, const float* __restrict__ Wa,
                          const float* __restrict__ Wb, const float* __restrict__ A_log,
                          const float* __restrict__ dt_bias, float* __restrict__ g,
                          float* __restrict__ bet)
{
  const int row = blockIdx.x * 4 + (threadIdx.x >> 6);
  const int lane = threadIdx.x & 63;
  float aA[6] = {0, 0, 0, 0, 0, 0}, aB[6] = {0, 0, 0, 0, 0, 0};
  const float* xr = x + (size_t)row * DD;
  for (int kk = 0; kk < 12; ++kk) {
    const int c = lane + kk * 64;
    const float xv = xr[c];
#pragma unroll
    for (int hh = 0; hh < 6; ++hh) { aA[hh] += xv * Wa[c * 6 + hh]; aB[hh] += xv * Wb[c * 6 + hh]; }
  }
#pragma unroll
  for (int hh = 0; hh < 6; ++hh) {
#pragma unroll
    for (int off = 32; off; off >>= 1) {
      aA[hh] += __shfl_xor(aA[hh], off, 64);
      aB[hh] += __shfl_xor(aB[hh], off, 64);
    }
  }
  if (lane == 0) {
    const int b = row >> 11, t = row & (TT - 1);
#pragma unroll
    for (int hh = 0; hh < 6; ++hh) {
      const float a = aA[hh] + dt_bias[hh];
      const float sp = (a > 20.f) ? a : log1pf(__expf(a));
      const size_t gi = ((size_t)(b * HH + hh)) * TT + t;
      g[gi] = -__expf(A_log[hh]) * sp;
      bet[gi] = 1.f / (1.f + __expf(-aB[hh]));
    }
  }
}

// ---------------- fused conv+SiLU+l2norm + gated delta rule ----------------
// grid (48, 4): block = (b*H+h, DV-quadrant of 64 cols), 256 threads = 4 waves.
// waves 0,1 (tid<128): k-channel loaders (conv fused); waves 2,3: q-channels;
// tid<64 additionally the 64 v-channels of this quadrant. l2norm folds into
// scalar factors inv_k/inv_q applied to the reduced dot products.
// thread (w,lane) owns S[32w..32w+31, jq*64+lane] in VGPRs.
__global__ __launch_bounds__(256) void delta_kernel(
    const __bf16* __restrict__ qpre, const __bf16* __restrict__ kpre,
    const __bf16* __restrict__ vpre,
    const float* __restrict__ cq, const float* __restrict__ ck,
    const float* __restrict__ cv,
    const float* __restrict__ g, const float* __restrict__ bet,
    __bf16* __restrict__ o)
{
  const int bh = blockIdx.x;
  const int b = bh / HH, h = bh - b * HH;
  const int jq = blockIdx.y;
  const int tid = threadIdx.x;
  const int lane = tid & 63, w = tid >> 6;
  __shared__ __align__(16) float kbuf[128];
  __shared__ __align__(16) float qbuf[128];
  __shared__ __align__(16) float vbuf[64];
  __shared__ float scal[2];
  __shared__ float red[4];
  __shared__ __align__(16) float redk[64][4];
  __shared__ __align__(16) float redo_[64][4];
  float S[32];
#pragma unroll
  for (int i = 0; i < 32; ++i) S[i] = 0.f;

  const bool isk = tid < 128;
  const int ch = isk ? tid : tid - 128;          // channel within head, 0..127
  const int qk_col = h * DKd + ch;               // col in [B*T,768] pre buffers
  const __bf16* pre = isk ? kpre : qpre;
  const size_t qkbase = (size_t)b * TT * DD + qk_col;
  const int v_col = h * DVd + jq * 64 + tid;     // valid for tid<64
  const size_t vbase = (size_t)b * TT * K2 + v_col;
  const size_t gbase = (size_t)bh * TT;
  const float4 wqk = isk ? *(const float4*)(ck + (size_t)qk_col * 4)
                         : *(const float4*)(cq + (size_t)qk_col * 4);
  float4 wv = make_float4(0.f, 0.f, 0.f, 0.f);
  if (tid < 64) wv = *(const float4*)(cv + (size_t)v_col * 4);

  // conv history (causal zero-pad) + t=0 prefetch
  float h0 = 0.f, h1 = 0.f, h2 = 0.f;
  float vh0 = 0.f, vh1 = 0.f, vh2 = 0.f;
  float pcur = (float)pre[qkbase];
  float pvcur = (tid < 64) ? (float)vpre[vbase] : 0.f;
  float psc = 0.f;
  if (tid == 224) psc = __expf(g[gbase]);
  if (tid == 225) psc = bet[gbase];

  const size_t obase = (size_t)bh * TT * DVd + jq * 64 + lane;
  for (int t = 0; t < TT; ++t) {
    // (a) conv + silu, commit raw (unnormalized) rows; per-wave ss reduce
    float y = h0 * wqk.x + h1 * wqk.y + h2 * wqk.z + pcur * wqk.w;
    y = y * sigm(y);
    if (isk) kbuf[ch] = y; else qbuf[ch] = y;
    if (tid < 64) {
      float yv = vh0 * wv.x + vh1 * wv.y + vh2 * wv.z + pvcur * wv.w;
      vbuf[tid] = yv * sigm(yv);
      vh0 = vh1; vh1 = vh2; vh2 = pvcur;
    }
    if (tid == 224) scal[0] = psc;
    if (tid == 225) scal[1] = psc;
    float ss = y * y;
#pragma unroll
    for (int off = 32; off; off >>= 1) ss += __shfl_xor(ss, off, 64);
    if (lane == 0) red[w] = ss;
    h0 = h1; h1 = h2; h2 = pcur;
    __syncthreads();                             // barrier A
    // (b) prefetch step t+1 (latency hides under compute)
    const int tn = (t + 1 < TT) ? (t + 1) : t;
    pcur = (float)pre[qkbase + (size_t)tn * DD];
    if (tid < 64) pvcur = (float)vpre[vbase + (size_t)tn * K2];
    if (tid == 224) psc = __expf(g[gbase + tn]);
    if (tid == 225) psc = bet[gbase + tn];
    const float invk = rsqrtf(red[0] + red[1] + 1e-6f);
    const float invq = rsqrtf(red[2] + red[3] + 1e-6f);
    const float eg = scal[0], btv = scal[1];
    // (c) partial y_k . S (pre-decay S; decay + norm folded in after reduce)
    float kr[32];
    float d0 = 0, d1 = 0, d2 = 0, d3 = 0;
#pragma unroll
    for (int ii = 0; ii < 8; ++ii) {
      const f32x4 kk = *(const f32x4*)(kbuf + w * 32 + ii * 4);
      kr[ii * 4 + 0] = kk[0]; kr[ii * 4 + 1] = kk[1];
      kr[ii * 4 + 2] = kk[2]; kr[ii * 4 + 3] = kk[3];
      d0 += kk[0] * S[ii * 4 + 0]; d1 += kk[1] * S[ii * 4 + 1];
      d2 += kk[2] * S[ii * 4 + 2]; d3 += kk[3] * S[ii * 4 + 3];
    }
    redk[lane][w] = (d0 + d1) + (d2 + d3);
    __syncthreads();                             // barrier B
    const f32x4 rk = *(const f32x4*)(&redk[lane][0]);
    const float sumk = (rk[0] + rk[1]) + (rk[2] + rk[3]);
    // v_new = beta*(v - k_norm.S_dec); S += outer(k_norm, v_new):
    // fold inv_k into the scalar: vn2 = inv_k * v_new
    const float vn2 = invk * (btv * (vbuf[lane] - invk * eg * sumk));
    // (d) S = eg*S + y_k*vn2 ; partial y_q . S_new
    float o0 = 0, o1 = 0, o2 = 0, o3 = 0;
#pragma unroll
    for (int ii = 0; ii < 8; ++ii) {
      const f32x4 qq = *(const f32x4*)(qbuf + w * 32 + ii * 4);
#pragma unroll
      for (int jj = 0; jj < 4; ++jj) {
        const int i = ii * 4 + jj;
        S[i] = S[i] * eg + kr[i] * vn2;
      }
      o0 += qq[0] * S[ii * 4 + 0]; o1 += qq[1] * S[ii * 4 + 1];
      o2 += qq[2] * S[ii * 4 + 2]; o3 += qq[3] * S[ii * 4 + 3];
    }
    redo_[lane][w] = (o0 + o1) + (o2 + o3);
    __syncthreads();                             // barrier C
    if (w == 0) {
      const f32x4 ro = *(const f32x4*)(&redo_[lane][0]);
      o[obase + (size_t)t * DVd] =
          (__bf16)(((ro[0] + ro[1]) + (ro[2] + ro[3])) * invq * 0.08838834764831845f);
    }
  }
}

// ---------------- gated RMSNorm epilogue + split-bf16 of o ----------------
// block per (m, h), 256 threads (one per DV element). Os compact [hi|lo].
__global__ void epilogue_kernel(const __bf16* __restrict__ o, const __bf16* __restrict__ gate,
                                const float* __restrict__ wn, __bf16* __restrict__ Os)
{
  const int bid = blockIdx.x;          // m*H + h
  const int m = bid / HH, h = bid - m * HH;
  const int b = m >> 11, t = m & (TT - 1);
  const int j = threadIdx.x;
  const float ov = (float)o[((size_t)(b * HH + h) * TT + t) * DVd + j];
  float ss = ov * ov;
#pragma unroll
  for (int off = 32; off; off >>= 1) ss += __shfl_xor(ss, off, 64);
  __shared__ float red[4];
  if ((j & 63) == 0) red[j >> 6] = ss;
  __syncthreads();
  const float inv = rsqrtf((red[0] + red[1] + red[2] + red[3]) * (1.f / DVd) + 1e-5f);
  const float gt = (float)gate[(size_t)m * K2 + h * DVd + j];
  const float val = ov * inv * wn[j] * (gt * sigm(gt));
  const __bf16 hi = (__bf16)val;
  const __bf16 lo = (__bf16)(val - (float)hi);
  const size_t ob = (size_t)m * (2 * K2) + h * DVd + j;
  Os[ob] = hi; Os[ob + K2] = lo;
}

// ---------------- ws-too-small sentinel: absmax ~= 1e7 + ws_MB ----------------
__global__ void sentinel_kernel(float* __restrict__ out, float val) {
  out[threadIdx.x] = val;
}

// ---------------- launch ----------------
extern "C" void kernel_launch(void* const* d_in, const int* in_sizes, int n_in,
                              void* d_out, int out_size, void* d_ws, size_t ws_size,
                              hipStream_t stream) {
  const float* x    = (const float*)d_in[0];
  const float* Wq   = (const float*)d_in[1];
  const float* Wk   = (const float*)d_in[2];
  const float* Wv   = (const float*)d_in[3];
  const float* Wa   = (const float*)d_in[4];
  const float* Wb   = (const float*)d_in[5];
  const float* Wg   = (const float*)d_in[6];
  const float* Wo   = (const float*)d_in[7];
  const float* cq   = (const float*)d_in[8];
  const float* ck   = (const float*)d_in[9];
  const float* cv   = (const float*)d_in[10];
  const float* Alog = (const float*)d_in[11];
  const float* dtb  = (const float*)d_in[12];
  const float* onw  = (const float*)d_in[13];
  float* out = (float*)d_out;
  uint8_t* ws = (uint8_t*)d_ws;

  // ---- workspace layout (bytes); lifetime-aliased. peak = 230,424,576 ----
  const size_t oGt = 0;                    // gate bf16 [16384,1536]   50,331,648  A->D
  const size_t oG  = oGt + 50331648;       // g f32 [48,2048]             393,216  A->C
  const size_t oBt = oG  + 393216;         // beta f32                    393,216  A->C
  const size_t oWo = oBt + 393216;         // Wo' bf16 [768,4608]       7,077,888  A->F
  const size_t oWq = oWo + 7077888;        // Wq' bf16 [768,2304]       3,538,944  A
  const size_t oWk = oWq + 3538944;
  const size_t oWv = oWk + 3538944;        // Wv' bf16 [1536,2304]      7,077,888  A
  const size_t oWg = oWv + 7077888;
  const size_t oXs = oWg + 7077888;        // Xs bf16 [16384,1536]     50,331,648  A
  const size_t oQp = oXs + 50331648;       // qpre bf16 [16384,768]    25,165,824  A->C
  const size_t oKp = oQp + 25165824;
  const size_t oVp = oKp + 25165824;       // vpre bf16 [16384,1536]   50,331,648  A->C
  const size_t total = oVp + 50331648;     // 230,424,576
  const size_t oO  = oXs;                  // o bf16 [B,H,T,256] over Xs (dead)  C->D
  const size_t oOs = oQp;                  // Os bf16 [16384,3072] over pre bufs D->F

  if (ws_size < total) {   // diagnostic: encodes ws MB in absmax
    sentinel_kernel<<<1, 256, 0, stream>>>(out, 1.0e7f + (float)(ws_size >> 20));
    return;
  }

  __bf16* Xs   = (__bf16*)(ws + oXs);
  __bf16* Wqp  = (__bf16*)(ws + oWq);
  __bf16* Wkp  = (__bf16*)(ws + oWk);
  __bf16* Wvp  = (__bf16*)(ws + oWv);
  __bf16* Wgp  = (__bf16*)(ws + oWg);
  __bf16* Wop  = (__bf16*)(ws + oWo);
  __bf16* qpre = (__bf16*)(ws + oQp);
  __bf16* kpre = (__bf16*)(ws + oKp);
  __bf16* vpre = (__bf16*)(ws + oVp);
  __bf16* gate = (__bf16*)(ws + oGt);
  float*  gbuf = (float*)(ws + oG);
  float*  bbuf = (float*)(ws + oBt);
  __bf16* oBuf = (__bf16*)(ws + oO);
  __bf16* Os   = (__bf16*)(ws + oOs);

  // phase A: conversions + projections
  convert_x_kernel<<<MM * DD / 256, 256, 0, stream>>>(x, Xs);
  convert_w_kernel<<<768 * 3 * K1 / 256, 256, 0, stream>>>(Wq, Wqp, K1, 768);
  convert_w_kernel<<<768 * 3 * K1 / 256, 256, 0, stream>>>(Wk, Wkp, K1, 768);
  convert_w_kernel<<<1536 * 3 * K1 / 256, 256, 0, stream>>>(Wv, Wvp, K1, 1536);
  convert_w_kernel<<<1536 * 3 * K1 / 256, 256, 0, stream>>>(Wg, Wgp, K1, 1536);
  convert_w_kernel<<<768 * 3 * K2 / 256, 256, 0, stream>>>(Wo, Wop, K2, 768);
  gemm_split<__bf16><<<dim3(128, 6),  256, 0, stream>>>(Xs, Wqp, qpre, 768,  K1);
  gemm_split<__bf16><<<dim3(128, 6),  256, 0, stream>>>(Xs, Wkp, kpre, 768,  K1);
  gemm_split<__bf16><<<dim3(128, 12), 256, 0, stream>>>(Xs, Wvp, vpre, 1536, K1);
  gemm_split<__bf16><<<dim3(128, 12), 256, 0, stream>>>(Xs, Wgp, gate, 1536, K1);
  gb_kernel<<<MM / 4, 256, 0, stream>>>(x, Wa, Wb, Alog, dtb, gbuf, bbuf);
  // phase C: fused conv/silu/l2norm + sequential gated delta rule
  delta_kernel<<<dim3(BB * HH, 4), 256, 0, stream>>>(qpre, kpre, vpre, cq, ck, cv,
                                                     gbuf, bbuf, oBuf);
  // phase D: gated RMSNorm + split-bf16, final projection
  epilogue_kernel<<<MM * HH, 256, 0, stream>>>(oBuf, gate, onw, Os);
  gemm_split<float><<<dim3(128, 6), 256, 0, stream>>>(Os, Wop, out, 768, K2);
}

// Round 3
// 2706.444 us; speedup vs baseline: 1.4760x; 1.4760x over previous
//
#include <hip/hip_runtime.h>
#include <hip/hip_bf16.h>
#include <stdint.h>

// ---------------- geometry ----------------
#define BB   8
#define TT   2048
#define DD   768
#define HH   6
#define DKd  128
#define DVd  256
#define MM   (BB*TT)      // 16384 rows
#define K1   768
#define K2   1536

typedef __bf16 bf16x8 __attribute__((ext_vector_type(8)));
typedef float  f32x4  __attribute__((ext_vector_type(4)));
typedef float  f32x2  __attribute__((ext_vector_type(2)));

__device__ __forceinline__ float sigm(float x) { return 1.f / (1.f + __expf(-x)); }

// ---------------- f32 -> split-bf16 conversions ----------------
// Logical A' = [Ahi | Ahi | Alo] (3K blocks), stored compact as [Ahi | Alo] (2K);
// GEMM staging maps logical k-block -> stored block. Weights Bt stored full 3K:
// [Bhi | Blo | Bhi] so A'.B'^T = Ahi.Bhi + Ahi.Blo + Alo.Bhi (~fp32 accuracy).

__global__ void convert_x_kernel(const float* __restrict__ x, __bf16* __restrict__ Xs) {
  int idx = blockIdx.x * 256 + threadIdx.x;
  if (idx >= MM * DD) return;
  int m = idx / DD, c = idx - m * DD;
  float v = x[idx];
  __bf16 h = (__bf16)v;
  __bf16 l = (__bf16)(v - (float)h);
  size_t base = (size_t)m * (2 * K1) + c;
  Xs[base] = h; Xs[base + K1] = l;
}

// W [K,N] f32 row-major -> Wt [N, 3K] bf16, k-blocks [hi | lo | hi]
__global__ void convert_w_kernel(const float* __restrict__ W, __bf16* __restrict__ Wt,
                                 int K, int N) {
  int idx = blockIdx.x * 256 + threadIdx.x;
  if (idx >= N * 3 * K) return;
  int n = idx / (3 * K), kk = idx - n * (3 * K);
  int blk = kk / K, k = kk - blk * K;
  float v = W[(size_t)k * N + n];
  __bf16 h = (__bf16)v;
  Wt[idx] = (blk == 1) ? (__bf16)(v - (float)h) : h;
}

// ---------------- bf16 MFMA GEMM: C[M,N] = A'[M,3K] * Bt[N,3K]^T ----------------
// A stored compact [M, 2K] = [hi|lo]; logical blocks [hi|hi|lo] via kc mapping.
// m97 structure: 128x128 tile, 4 waves (2x2), BK=32, global_load_lds width 16.
template <typename OutT>
__global__ __launch_bounds__(256) void gemm_split(
    const __bf16* __restrict__ A, const __bf16* __restrict__ Bt,
    OutT* __restrict__ C, int N, int Khi)
{
  __shared__ __bf16 Als[128 * 32];
  __shared__ __bf16 Bls[128 * 32];
  const int LDA = 2 * Khi, Klog = 3 * Khi;
  const int tid = threadIdx.x;
  const int lane = tid & 63, w = tid >> 6;
  const int wr = w >> 1, wc = w & 1;
  const int bm = blockIdx.x, bn = blockIdx.y;
  f32x4 acc[4][4] = {};
  const __bf16* Ab = A + (size_t)bm * 128 * LDA;
  const __bf16* Bb = Bt + (size_t)bn * 128 * Klog;
  const int r0 = tid >> 2, co0 = (tid & 3) * 8;
  const int r1 = (256 + tid) >> 2, co1 = ((256 + tid) & 3) * 8;
  for (int k0 = 0; k0 < Klog; k0 += 32) {
    const int kc = (k0 < Khi) ? k0 : k0 - Khi;   // [hi|hi|lo] -> [hi|lo]
    __syncthreads();
    __builtin_amdgcn_global_load_lds(
        (const __attribute__((address_space(1))) void*)(Ab + (size_t)r0 * LDA + kc + co0),
        (__attribute__((address_space(3))) void*)(Als + (w * 64) * 8), 16, 0, 0);
    __builtin_amdgcn_global_load_lds(
        (const __attribute__((address_space(1))) void*)(Ab + (size_t)r1 * LDA + kc + co1),
        (__attribute__((address_space(3))) void*)(Als + (256 + w * 64) * 8), 16, 0, 0);
    __builtin_amdgcn_global_load_lds(
        (const __attribute__((address_space(1))) void*)(Bb + (size_t)r0 * Klog + k0 + co0),
        (__attribute__((address_space(3))) void*)(Bls + (w * 64) * 8), 16, 0, 0);
    __builtin_amdgcn_global_load_lds(
        (const __attribute__((address_space(1))) void*)(Bb + (size_t)r1 * Klog + k0 + co1),
        (__attribute__((address_space(3))) void*)(Bls + (256 + w * 64) * 8), 16, 0, 0);
    __syncthreads();
    bf16x8 af[4], bfr[4];
    const int rb = wr * 64 + (lane & 15);
    const int kb = (lane >> 4) * 8;
#pragma unroll
    for (int i = 0; i < 4; ++i) af[i] = *(const bf16x8*)(Als + (rb + i * 16) * 32 + kb);
    const int cb = wc * 64 + (lane & 15);
#pragma unroll
    for (int i = 0; i < 4; ++i) bfr[i] = *(const bf16x8*)(Bls + (cb + i * 16) * 32 + kb);
#pragma unroll
    for (int mi = 0; mi < 4; ++mi)
#pragma unroll
      for (int ni = 0; ni < 4; ++ni)
        acc[mi][ni] = __builtin_amdgcn_mfma_f32_16x16x32_bf16(af[mi], bfr[ni], acc[mi][ni], 0, 0, 0);
  }
  const int row0 = bm * 128 + wr * 64;
  const int col0 = bn * 128 + wc * 64 + (lane & 15);
  const int rsub = (lane >> 4) * 4;
#pragma unroll
  for (int mi = 0; mi < 4; ++mi)
#pragma unroll
    for (int ni = 0; ni < 4; ++ni)
#pragma unroll
      for (int r = 0; r < 4; ++r) {
        int row = row0 + mi * 16 + rsub + r;
        C[(size_t)row * N + col0 + ni * 16] = (OutT)acc[mi][ni][r];
      }
}

// ---------------- g / beta projections (N=6 each, direct fp32) ----------------
__global__ void gb_kernel(const float* __restrict__ x, const float* __restrict__ Wa,
                          const float* __restrict__ Wb, const float* __restrict__ A_log,
                          const float* __restrict__ dt_bias, float* __restrict__ g,
                          float* __restrict__ bet)
{
  const int row = blockIdx.x * 4 + (threadIdx.x >> 6);
  const int lane = threadIdx.x & 63;
  float aA[6] = {0, 0, 0, 0, 0, 0}, aB[6] = {0, 0, 0, 0, 0, 0};
  const float* xr = x + (size_t)row * DD;
  for (int kk = 0; kk < 12; ++kk) {
    const int c = lane + kk * 64;
    const float xv = xr[c];
#pragma unroll
    for (int hh = 0; hh < 6; ++hh) { aA[hh] += xv * Wa[c * 6 + hh]; aB[hh] += xv * Wb[c * 6 + hh]; }
  }
#pragma unroll
  for (int hh = 0; hh < 6; ++hh) {
#pragma unroll
    for (int off = 32; off; off >>= 1) {
      aA[hh] += __shfl_xor(aA[hh], off, 64);
      aB[hh] += __shfl_xor(aB[hh], off, 64);
    }
  }
  if (lane == 0) {
    const int b = row >> 11, t = row & (TT - 1);
#pragma unroll
    for (int hh = 0; hh < 6; ++hh) {
      const float a = aA[hh] + dt_bias[hh];
      const float sp = (a > 20.f) ? a : log1pf(__expf(a));
      const size_t gi = ((size_t)(b * HH + hh)) * TT + t;
      g[gi] = -__expf(A_log[hh]) * sp;
      bet[gi] = 1.f / (1.f + __expf(-aB[hh]));
    }
  }
}

// ---------------- fused conv+SiLU+l2norm + gated delta rule (v2) ----------------
// grid (48, 4): block = (b*H+h, DV-quadrant of 64 cols), 256 threads = 4 waves.
// S ownership: thread (w, lane) with rg=lane>>3, cg=lane&7 owns
//   S[rg*16 .. rg*16+16) x quadrant-cols {w*16+cg*2, +1}.
// Row reductions (k.S, q.S) = 3 in-wave shfl_xor rounds (masks 8/16/32) -> no
// cross-wave LDS reduce. 4 t-steps staged per barrier, double-buffered LDS.
// Loader roles (independent of compute mapping): tid<128 -> k channel tid
// (conv+silu), tid>=128 -> q channel; tid<64 also v channel; tid 192..199 scal.
__global__ __launch_bounds__(256) void delta_kernel(
    const __bf16* __restrict__ qpre, const __bf16* __restrict__ kpre,
    const __bf16* __restrict__ vpre,
    const float* __restrict__ cq, const float* __restrict__ ck,
    const float* __restrict__ cv,
    const float* __restrict__ g, const float* __restrict__ bet,
    __bf16* __restrict__ o)
{
  const int bh = blockIdx.x;
  const int b = bh / HH, h = bh - b * HH;
  const int jq = blockIdx.y;
  const int tid = threadIdx.x;
  const int lane = tid & 63, w = tid >> 6;
  const int rg = lane >> 3;      // 0..7
  const int cg = lane & 7;       // 0..7

  // padded [8 rowgroups][20] so the 8 broadcast b128 reads cover distinct bank-quads
  __shared__ __align__(16) float kq[2][4][2][160];
  __shared__ __align__(16) float vb[2][4][64];
  __shared__ __align__(16) float rd[2][4][4];
  __shared__ __align__(16) float sc2[2][4][2];

  float S0[16], S1[16];
#pragma unroll
  for (int i = 0; i < 16; ++i) { S0[i] = 0.f; S1[i] = 0.f; }

  // ---- loader roles ----
  const bool isk = tid < 128;
  const int ch = isk ? tid : tid - 128;
  const int rrole = isk ? 0 : 1;
  const int qk_col = h * DKd + ch;
  const __bf16* pre = isk ? kpre : qpre;
  const size_t qkbase = (size_t)b * TT * DD + qk_col;
  const float4 wqk = isk ? *(const float4*)(ck + (size_t)qk_col * 4)
                         : *(const float4*)(cq + (size_t)qk_col * 4);
  const bool isv = tid < 64;
  const int v_col = h * DVd + jq * 64 + tid;
  const size_t vbase = (size_t)b * TT * K2 + v_col;
  float4 wv = make_float4(0.f, 0.f, 0.f, 0.f);
  if (isv) wv = *(const float4*)(cv + (size_t)v_col * 4);
  const bool issc = (tid >= 192) && (tid < 200);
  const int scs = tid & 3;            // step slot
  const int scw = (tid >> 2) & 1;     // 0: exp(g), 1: beta
  const size_t gbase = (size_t)bh * TT;
  const int kwi = (ch >> 4) * 20 + (ch & 15);

  // conv history (causal zero-pad) + group-0 prefetch
  float h0 = 0.f, h1 = 0.f, h2 = 0.f, vh0 = 0.f, vh1 = 0.f, vh2 = 0.f;
  float curk[4], curv[4] = {0.f, 0.f, 0.f, 0.f}, scv = 0.f;
#pragma unroll
  for (int s = 0; s < 4; ++s) curk[s] = (float)pre[qkbase + (size_t)s * DD];
  if (isv) {
#pragma unroll
    for (int s = 0; s < 4; ++s) curv[s] = (float)vpre[vbase + (size_t)s * K2];
  }
  if (issc) scv = scw ? bet[gbase + scs] : g[gbase + scs];

  const size_t obase = (size_t)bh * TT * DVd + jq * 64 + w * 16 + cg * 2;
  const float scale = 0.08838834764831845f;   // DK^-0.5

  for (int grp = 0; grp < TT / 4; ++grp) {
    const int d = grp & 1;
    const int t0 = grp * 4;
    // ---- commit phase: conv+silu for 4 steps into LDS[d] ----
    float ss[4];
#pragma unroll
    for (int s = 0; s < 4; ++s) {
      float y = h0 * wqk.x + h1 * wqk.y + h2 * wqk.z + curk[s] * wqk.w;
      y = y * sigm(y);
      kq[d][s][rrole][kwi] = y;
      ss[s] = y * y;
      h0 = h1; h1 = h2; h2 = curk[s];
    }
    if (isv) {
#pragma unroll
      for (int s = 0; s < 4; ++s) {
        float yv = vh0 * wv.x + vh1 * wv.y + vh2 * wv.z + curv[s] * wv.w;
        vb[d][s][tid] = yv * sigm(yv);
        vh0 = vh1; vh1 = vh2; vh2 = curv[s];
      }
    }
#pragma unroll
    for (int m = 1; m < 64; m <<= 1) {
#pragma unroll
      for (int s = 0; s < 4; ++s) ss[s] += __shfl_xor(ss[s], m, 64);
    }
    if (lane == 0) {
#pragma unroll
      for (int s = 0; s < 4; ++s) rd[d][s][w] = ss[s];
    }
    if (issc) sc2[d][scs][scw] = scw ? scv : __expf(scv);
    // ---- prefetch next group into registers (hides under barrier+compute) ----
    {
      const int tb = t0 + 4;
#pragma unroll
      for (int s = 0; s < 4; ++s) {
        const int tn = (tb + s < TT) ? (tb + s) : (TT - 1);
        curk[s] = (float)pre[qkbase + (size_t)tn * DD];
      }
      if (isv) {
#pragma unroll
        for (int s = 0; s < 4; ++s) {
          const int tn = (tb + s < TT) ? (tb + s) : (TT - 1);
          curv[s] = (float)vpre[vbase + (size_t)tn * K2];
        }
      }
      if (issc) {
        const int tn = (tb + scs < TT) ? (tb + scs) : (TT - 1);
        scv = scw ? bet[gbase + tn] : g[gbase + tn];
      }
    }
    __syncthreads();
    // ---- compute phase: 4 sequential scan steps, no barriers ----
#pragma unroll
    for (int s = 0; s < 4; ++s) {
      const float* kbase = &kq[d][s][0][rg * 20];
      const float* qbase = &kq[d][s][1][rg * 20];
      const f32x4 ka = *(const f32x4*)(kbase + 0);
      const f32x4 kb2 = *(const f32x4*)(kbase + 4);
      const f32x4 kc2 = *(const f32x4*)(kbase + 8);
      const f32x4 kd2 = *(const f32x4*)(kbase + 12);
      const f32x4 qa = *(const f32x4*)(qbase + 0);
      const f32x4 qb2 = *(const f32x4*)(qbase + 4);
      const f32x4 qc2 = *(const f32x4*)(qbase + 8);
      const f32x4 qd2 = *(const f32x4*)(qbase + 12);
      const f32x2 vv = *(const f32x2*)&vb[d][s][w * 16 + cg * 2];
      const f32x4 rdv = *(const f32x4*)&rd[d][s][0];
      const f32x2 scp = *(const f32x2*)&sc2[d][s][0];
      float kr[16], qr[16];
#pragma unroll
      for (int i = 0; i < 4; ++i) {
        kr[i] = ka[i]; kr[4 + i] = kb2[i]; kr[8 + i] = kc2[i]; kr[12 + i] = kd2[i];
        qr[i] = qa[i]; qr[4 + i] = qb2[i]; qr[8 + i] = qc2[i]; qr[12 + i] = qd2[i];
      }
      float sk0 = 0.f, sk1 = 0.f;
#pragma unroll
      for (int i = 0; i < 16; ++i) { sk0 += kr[i] * S0[i]; sk1 += kr[i] * S1[i]; }
      sk0 += __shfl_xor(sk0, 8, 64);  sk1 += __shfl_xor(sk1, 8, 64);
      sk0 += __shfl_xor(sk0, 16, 64); sk1 += __shfl_xor(sk1, 16, 64);
      sk0 += __shfl_xor(sk0, 32, 64); sk1 += __shfl_xor(sk1, 32, 64);
      const float eg = scp[0], btv = scp[1];
      const float invk = rsqrtf(rdv[0] + rdv[1] + 1e-6f);
      const float invq = rsqrtf(rdv[2] + rdv[3] + 1e-6f);
      const float cc = invk * eg;
      const float vn0 = invk * (btv * (vv[0] - cc * sk0));
      const float vn1 = invk * (btv * (vv[1] - cc * sk1));
      float so0 = 0.f, so1 = 0.f;
#pragma unroll
      for (int i = 0; i < 16; ++i) {
        S0[i] = S0[i] * eg + kr[i] * vn0;
        S1[i] = S1[i] * eg + kr[i] * vn1;
        so0 += qr[i] * S0[i];
        so1 += qr[i] * S1[i];
      }
      so0 += __shfl_xor(so0, 8, 64);  so1 += __shfl_xor(so1, 8, 64);
      so0 += __shfl_xor(so0, 16, 64); so1 += __shfl_xor(so1, 16, 64);
      so0 += __shfl_xor(so0, 32, 64); so1 += __shfl_xor(so1, 32, 64);
      if (rg == 0) {
        const float f0 = so0 * invq * scale;
        const float f1 = so1 * invq * scale;
        const __bf16 b0 = (__bf16)f0, b1 = (__bf16)f1;
        const uint32_t pk = ((uint32_t)(*(const uint16_t*)&b1) << 16) |
                            (uint32_t)(*(const uint16_t*)&b0);
        *(uint32_t*)(o + obase + (size_t)(t0 + s) * DVd) = pk;
      }
    }
  }
}

// ---------------- gated RMSNorm epilogue + split-bf16 of o ----------------
__global__ void epilogue_kernel(const __bf16* __restrict__ o, const __bf16* __restrict__ gate,
                                const float* __restrict__ wn, __bf16* __restrict__ Os)
{
  const int bid = blockIdx.x;          // m*H + h
  const int m = bid / HH, h = bid - m * HH;
  const int b = m >> 11, t = m & (TT - 1);
  const int j = threadIdx.x;
  const float ov = (float)o[((size_t)(b * HH + h) * TT + t) * DVd + j];
  float ss = ov * ov;
#pragma unroll
  for (int off = 32; off; off >>= 1) ss += __shfl_xor(ss, off, 64);
  __shared__ float red[4];
  if ((j & 63) == 0) red[j >> 6] = ss;
  __syncthreads();
  const float inv = rsqrtf((red[0] + red[1] + red[2] + red[3]) * (1.f / DVd) + 1e-5f);
  const float gt = (float)gate[(size_t)m * K2 + h * DVd + j];
  const float val = ov * inv * wn[j] * (gt * sigm(gt));
  const __bf16 hi = (__bf16)val;
  const __bf16 lo = (__bf16)(val - (float)hi);
  const size_t ob = (size_t)m * (2 * K2) + h * DVd + j;
  Os[ob] = hi; Os[ob + K2] = lo;
}

// ---------------- ws-too-small sentinel: absmax ~= 1e7 + ws_MB ----------------
__global__ void sentinel_kernel(float* __restrict__ out, float val) {
  out[threadIdx.x] = val;
}

// ---------------- launch ----------------
extern "C" void kernel_launch(void* const* d_in, const int* in_sizes, int n_in,
                              void* d_out, int out_size, void* d_ws, size_t ws_size,
                              hipStream_t stream) {
  const float* x    = (const float*)d_in[0];
  const float* Wq   = (const float*)d_in[1];
  const float* Wk   = (const float*)d_in[2];
  const float* Wv   = (const float*)d_in[3];
  const float* Wa   = (const float*)d_in[4];
  const float* Wb   = (const float*)d_in[5];
  const float* Wg   = (const float*)d_in[6];
  const float* Wo   = (const float*)d_in[7];
  const float* cq   = (const float*)d_in[8];
  const float* ck   = (const float*)d_in[9];
  const float* cv   = (const float*)d_in[10];
  const float* Alog = (const float*)d_in[11];
  const float* dtb  = (const float*)d_in[12];
  const float* onw  = (const float*)d_in[13];
  float* out = (float*)d_out;
  uint8_t* ws = (uint8_t*)d_ws;

  // ---- workspace layout (bytes); lifetime-aliased. peak = 230,424,576 ----
  const size_t oGt = 0;                    // gate bf16 [16384,1536]   50,331,648
  const size_t oG  = oGt + 50331648;       // g f32 [48,2048]             393,216
  const size_t oBt = oG  + 393216;         // beta f32                    393,216
  const size_t oWo = oBt + 393216;         // Wo' bf16 [768,4608]       7,077,888
  const size_t oWq = oWo + 7077888;        // Wq' bf16 [768,2304]       3,538,944
  const size_t oWk = oWq + 3538944;
  const size_t oWv = oWk + 3538944;        // Wv' bf16 [1536,2304]      7,077,888
  const size_t oWg = oWv + 7077888;
  const size_t oXs = oWg + 7077888;        // Xs bf16 [16384,1536]     50,331,648
  const size_t oQp = oXs + 50331648;       // qpre bf16 [16384,768]    25,165,824
  const size_t oKp = oQp + 25165824;
  const size_t oVp = oKp + 25165824;       // vpre bf16 [16384,1536]   50,331,648
  const size_t total = oVp + 50331648;     // 230,424,576
  const size_t oO  = oXs;                  // o bf16 over Xs (dead after GEMMs)
  const size_t oOs = oQp;                  // Os bf16 over pre bufs (dead after delta)

  if (ws_size < total) {   // diagnostic: encodes ws MB in absmax
    sentinel_kernel<<<1, 256, 0, stream>>>(out, 1.0e7f + (float)(ws_size >> 20));
    return;
  }

  __bf16* Xs   = (__bf16*)(ws + oXs);
  __bf16* Wqp  = (__bf16*)(ws + oWq);
  __bf16* Wkp  = (__bf16*)(ws + oWk);
  __bf16* Wvp  = (__bf16*)(ws + oWv);
  __bf16* Wgp  = (__bf16*)(ws + oWg);
  __bf16* Wop  = (__bf16*)(ws + oWo);
  __bf16* qpre = (__bf16*)(ws + oQp);
  __bf16* kpre = (__bf16*)(ws + oKp);
  __bf16* vpre = (__bf16*)(ws + oVp);
  __bf16* gate = (__bf16*)(ws + oGt);
  float*  gbuf = (float*)(ws + oG);
  float*  bbuf = (float*)(ws + oBt);
  __bf16* oBuf = (__bf16*)(ws + oO);
  __bf16* Os   = (__bf16*)(ws + oOs);

  // phase A: conversions + projections
  convert_x_kernel<<<MM * DD / 256, 256, 0, stream>>>(x, Xs);
  convert_w_kernel<<<768 * 3 * K1 / 256, 256, 0, stream>>>(Wq, Wqp, K1, 768);
  convert_w_kernel<<<768 * 3 * K1 / 256, 256, 0, stream>>>(Wk, Wkp, K1, 768);
  convert_w_kernel<<<1536 * 3 * K1 / 256, 256, 0, stream>>>(Wv, Wvp, K1, 1536);
  convert_w_kernel<<<1536 * 3 * K1 / 256, 256, 0, stream>>>(Wg, Wgp, K1, 1536);
  convert_w_kernel<<<768 * 3 * K2 / 256, 256, 0, stream>>>(Wo, Wop, K2, 768);
  gemm_split<__bf16><<<dim3(128, 6),  256, 0, stream>>>(Xs, Wqp, qpre, 768,  K1);
  gemm_split<__bf16><<<dim3(128, 6),  256, 0, stream>>>(Xs, Wkp, kpre, 768,  K1);
  gemm_split<__bf16><<<dim3(128, 12), 256, 0, stream>>>(Xs, Wvp, vpre, 1536, K1);
  gemm_split<__bf16><<<dim3(128, 12), 256, 0, stream>>>(Xs, Wgp, gate, 1536, K1);
  gb_kernel<<<MM / 4, 256, 0, stream>>>(x, Wa, Wb, Alog, dtb, gbuf, bbuf);
  // phase C: fused conv/silu/l2norm + sequential gated delta rule
  delta_kernel<<<dim3(BB * HH, 4), 256, 0, stream>>>(qpre, kpre, vpre, cq, ck, cv,
                                                     gbuf, bbuf, oBuf);
  // phase D: gated RMSNorm + split-bf16, final projection
  epilogue_kernel<<<MM * HH, 256, 0, stream>>>(oBuf, gate, onw, Os);
  gemm_split<float><<<dim3(128, 6), 256, 0, stream>>>(Os, Wop, out, 768, K2);
}

// Round 5
// 1752.786 us; speedup vs baseline: 2.2790x; 1.5441x over previous
//
#include <hip/hip_runtime.h>
#include <hip/hip_bf16.h>
#include <stdint.h>

// ---------------- geometry ----------------
#define BB   8
#define TT   2048
#define DD   768
#define HH   6
#define DKd  128
#define DVd  256
#define MM   (BB*TT)      // 16384 rows
#define K1   768
#define K2   1536
#define CC   32           // delta chunk length

typedef __bf16 bf16x8 __attribute__((ext_vector_type(8)));
typedef __bf16 bf16x4 __attribute__((ext_vector_type(4)));
typedef float  f32x4  __attribute__((ext_vector_type(4)));

__device__ __forceinline__ float sigm(float x) { return 1.f / (1.f + __expf(-x)); }
__device__ __forceinline__ void split2(float v, __bf16& hi, __bf16& lo) {
  hi = (__bf16)v; lo = (__bf16)(v - (float)hi);
}
__device__ __forceinline__ f32x4 mfma3(bf16x8 ah, bf16x8 al, bf16x8 bh_, bf16x8 bl_, f32x4 acc) {
  acc = __builtin_amdgcn_mfma_f32_16x16x32_bf16(ah, bh_, acc, 0, 0, 0);
  acc = __builtin_amdgcn_mfma_f32_16x16x32_bf16(ah, bl_, acc, 0, 0, 0);
  acc = __builtin_amdgcn_mfma_f32_16x16x32_bf16(al, bh_, acc, 0, 0, 0);
  return acc;
}

// ---------------- f32 -> split-bf16 conversions ----------------
__global__ void convert_x_kernel(const float* __restrict__ x, __bf16* __restrict__ Xs) {
  int idx = blockIdx.x * 256 + threadIdx.x;
  if (idx >= MM * DD) return;
  int m = idx / DD, c = idx - m * DD;
  float v = x[idx];
  __bf16 h = (__bf16)v;
  __bf16 l = (__bf16)(v - (float)h);
  size_t base = (size_t)m * (2 * K1) + c;
  Xs[base] = h; Xs[base + K1] = l;
}

__global__ void convert_w_kernel(const float* __restrict__ W, __bf16* __restrict__ Wt,
                                 int K, int N) {
  int idx = blockIdx.x * 256 + threadIdx.x;
  if (idx >= N * 3 * K) return;
  int n = idx / (3 * K), kk = idx - n * (3 * K);
  int blk = kk / K, k = kk - blk * K;
  float v = W[(size_t)k * N + n];
  __bf16 h = (__bf16)v;
  Wt[idx] = (blk == 1) ? (__bf16)(v - (float)h) : h;
}

// ---------------- bf16 MFMA GEMM: C[M,N] = A'[M,3K] * Bt[N,3K]^T ----------------
template <typename OutT>
__global__ __launch_bounds__(256) void gemm_split(
    const __bf16* __restrict__ A, const __bf16* __restrict__ Bt,
    OutT* __restrict__ C, int N, int Khi)
{
  __shared__ __bf16 Als[128 * 32];
  __shared__ __bf16 Bls[128 * 32];
  const int LDA = 2 * Khi, Klog = 3 * Khi;
  const int tid = threadIdx.x;
  const int lane = tid & 63, w = tid >> 6;
  const int wr = w >> 1, wc = w & 1;
  const int bm = blockIdx.x, bn = blockIdx.y;
  f32x4 acc[4][4] = {};
  const __bf16* Ab = A + (size_t)bm * 128 * LDA;
  const __bf16* Bb = Bt + (size_t)bn * 128 * Klog;
  const int r0 = tid >> 2, co0 = (tid & 3) * 8;
  const int r1 = (256 + tid) >> 2, co1 = ((256 + tid) & 3) * 8;
  for (int k0 = 0; k0 < Klog; k0 += 32) {
    const int kc = (k0 < Khi) ? k0 : k0 - Khi;
    __syncthreads();
    __builtin_amdgcn_global_load_lds(
        (const __attribute__((address_space(1))) void*)(Ab + (size_t)r0 * LDA + kc + co0),
        (__attribute__((address_space(3))) void*)(Als + (w * 64) * 8), 16, 0, 0);
    __builtin_amdgcn_global_load_lds(
        (const __attribute__((address_space(1))) void*)(Ab + (size_t)r1 * LDA + kc + co1),
        (__attribute__((address_space(3))) void*)(Als + (256 + w * 64) * 8), 16, 0, 0);
    __builtin_amdgcn_global_load_lds(
        (const __attribute__((address_space(1))) void*)(Bb + (size_t)r0 * Klog + k0 + co0),
        (__attribute__((address_space(3))) void*)(Bls + (w * 64) * 8), 16, 0, 0);
    __builtin_amdgcn_global_load_lds(
        (const __attribute__((address_space(1))) void*)(Bb + (size_t)r1 * Klog + k0 + co1),
        (__attribute__((address_space(3))) void*)(Bls + (256 + w * 64) * 8), 16, 0, 0);
    __syncthreads();
    bf16x8 af[4], bfr[4];
    const int rb = wr * 64 + (lane & 15);
    const int kb = (lane >> 4) * 8;
#pragma unroll
    for (int i = 0; i < 4; ++i) af[i] = *(const bf16x8*)(Als + (rb + i * 16) * 32 + kb);
    const int cb = wc * 64 + (lane & 15);
#pragma unroll
    for (int i = 0; i < 4; ++i) bfr[i] = *(const bf16x8*)(Bls + (cb + i * 16) * 32 + kb);
#pragma unroll
    for (int mi = 0; mi < 4; ++mi)
#pragma unroll
      for (int ni = 0; ni < 4; ++ni)
        acc[mi][ni] = __builtin_amdgcn_mfma_f32_16x16x32_bf16(af[mi], bfr[ni], acc[mi][ni], 0, 0, 0);
  }
  const int row0 = bm * 128 + wr * 64;
  const int col0 = bn * 128 + wc * 64 + (lane & 15);
  const int rsub = (lane >> 4) * 4;
#pragma unroll
  for (int mi = 0; mi < 4; ++mi)
#pragma unroll
    for (int ni = 0; ni < 4; ++ni)
#pragma unroll
      for (int r = 0; r < 4; ++r) {
        int row = row0 + mi * 16 + rsub + r;
        C[(size_t)row * N + col0 + ni * 16] = (OutT)acc[mi][ni][r];
      }
}

// ---------------- g / beta projections ----------------
__global__ void gb_kernel(const float* __restrict__ x, const float* __restrict__ Wa,
                          const float* __restrict__ Wb, const float* __restrict__ A_log,
                          const float* __restrict__ dt_bias, float* __restrict__ g,
                          float* __restrict__ bet)
{
  const int row = blockIdx.x * 4 + (threadIdx.x >> 6);
  const int lane = threadIdx.x & 63;
  float aA[6] = {0, 0, 0, 0, 0, 0}, aB[6] = {0, 0, 0, 0, 0, 0};
  const float* xr = x + (size_t)row * DD;
  for (int kk = 0; kk < 12; ++kk) {
    const int c = lane + kk * 64;
    const float xv = xr[c];
#pragma unroll
    for (int hh = 0; hh < 6; ++hh) { aA[hh] += xv * Wa[c * 6 + hh]; aB[hh] += xv * Wb[c * 6 + hh]; }
  }
#pragma unroll
  for (int hh = 0; hh < 6; ++hh) {
#pragma unroll
    for (int off = 32; off; off >>= 1) {
      aA[hh] += __shfl_xor(aA[hh], off, 64);
      aB[hh] += __shfl_xor(aB[hh], off, 64);
    }
  }
  if (lane == 0) {
    const int b = row >> 11, t = row & (TT - 1);
#pragma unroll
    for (int hh = 0; hh < 6; ++hh) {
      const float a = aA[hh] + dt_bias[hh];
      const float sp = (a > 20.f) ? a : log1pf(__expf(a));
      const size_t gi = ((size_t)(b * HH + hh)) * TT + t;
      g[gi] = -__expf(A_log[hh]) * sp;
      bet[gi] = 1.f / (1.f + __expf(-aB[hh]));
    }
  }
}

// ---------------- chunked gated delta rule (UT transform, MFMA) ----------------
// grid (48,4): (b*H+h, DV-quarter). 256 thr = 4 waves. Chunks of CC=32.
// All matrices in LDS as bf16 hi/lo pairs; S,V' stored transposed so MFMA
// B-fragments are direct ds_read_b128.
__global__ __launch_bounds__(256) void delta_kernel(
    const __bf16* __restrict__ qpre, const __bf16* __restrict__ kpre,
    const __bf16* __restrict__ vpre,
    const float* __restrict__ cq, const float* __restrict__ ck,
    const float* __restrict__ cv,
    const float* __restrict__ g, const float* __restrict__ bet,
    __bf16* __restrict__ o)
{
  const int bh = blockIdx.x, b = bh / HH, h = bh - b * HH;
  const int jq = blockIdx.y;
  const int tid = threadIdx.x, lane = tid & 63, w = tid >> 6;
  const int r16 = lane & 15, g2 = lane >> 4;

  __shared__ __align__(16) __bf16 Khi[32][136], Klo[32][136];
  __shared__ __align__(16) __bf16 Qhi[32][136], Qlo[32][136];
  __shared__ __align__(16) __bf16 SThi[64][136], STlo[64][136];   // S^T [c][d]
  __shared__ __align__(16) __bf16 Ahi[32][40],  Alo[32][40];
  __shared__ __align__(16) __bf16 Phi[32][40],  Plo[32][40];
  __shared__ __align__(16) __bf16 VThi[64][40], VTlo[64][40];     // V'^T [c][t]
  __shared__ __align__(16) __bf16 GThi[64][16], GTlo[64][16];
  __shared__ __align__(16) __bf16 Thi[4][16][24], Tlo[4][16][24]; // slots 2,3 scratch
  __shared__ __align__(16) float  RHSb[32][66];
  __shared__ __align__(16) float  cwkq[256][4];
  __shared__ __align__(16) float  cwv[64][4];
  __shared__ float Lv[32], Bv[32], BBv[32], BCb[32], Bb2[32];

  // conv weights (k: rows 0..127, q: 128..255)
  {
    const float* src = (tid < 128) ? ck + (size_t)(h * DKd + tid) * 4
                                   : cq + (size_t)(h * DKd + (tid - 128)) * 4;
    *(float4*)&cwkq[tid][0] = *(const float4*)src;
    if (tid < 64) *(float4*)&cwv[tid][0] = *(const float4*)(cv + (size_t)(h * DVd + jq * 64 + tid) * 4);
  }
  // zero S^T
  for (int i = tid; i < 1088; i += 256) {
    ((uint4*)SThi)[i] = make_uint4(0, 0, 0, 0);
    ((uint4*)STlo)[i] = make_uint4(0, 0, 0, 0);
  }
  __syncthreads();

  const size_t gbase = (size_t)bh * TT;
  const size_t obase = (size_t)bh * TT * DVd + jq * 64;
  const bf16x8 z8 = {};

  for (int chk = 0; chk < TT / CC; ++chk) {
    const int t0 = chk * CC;
    // ================= stage 0: conv + silu (+ l2norm), decay scan ============
    {
      const int r = tid >> 3, cg = tid & 7;
      const int tG = t0 + r;
      // ---- K ----
      {
        bf16x8 tp0[4], tp1[4];
#pragma unroll
        for (int i = 0; i < 4; ++i) {
          int t = tG - 3 + i;
          if (t >= 0) {
            const __bf16* p = kpre + ((size_t)(b * TT + t)) * DD + h * DKd + cg * 16;
            tp0[i] = *(const bf16x8*)p; tp1[i] = *(const bf16x8*)(p + 8);
          } else { tp0[i] = z8; tp1[i] = z8; }
        }
        float ss = 0.f;
#pragma unroll
        for (int c = 0; c < 16; ++c) {
          const float4 w4 = *(const float4*)&cwkq[cg * 16 + c][0];
          const int j = c & 7;
          float y = (c < 8)
              ? (w4.x * (float)tp0[0][j] + w4.y * (float)tp0[1][j] + w4.z * (float)tp0[2][j] + w4.w * (float)tp0[3][j])
              : (w4.x * (float)tp1[0][j] + w4.y * (float)tp1[1][j] + w4.z * (float)tp1[2][j] + w4.w * (float)tp1[3][j]);
          y = y * sigm(y);
          ss += y * y;
          __bf16 hi, lo; split2(y, hi, lo);
          Khi[r][cg * 16 + c] = hi; Klo[r][cg * 16 + c] = lo;
        }
        ss += __shfl_xor(ss, 1, 64); ss += __shfl_xor(ss, 2, 64); ss += __shfl_xor(ss, 4, 64);
        const float inv = rsqrtf(ss + 1e-6f);
#pragma unroll
        for (int c = 0; c < 16; ++c) {
          float v = ((float)Khi[r][cg * 16 + c] + (float)Klo[r][cg * 16 + c]) * inv;
          __bf16 hi, lo; split2(v, hi, lo);
          Khi[r][cg * 16 + c] = hi; Klo[r][cg * 16 + c] = lo;
        }
      }
      // ---- Q (scale folded) ----
      {
        bf16x8 tp0[4], tp1[4];
#pragma unroll
        for (int i = 0; i < 4; ++i) {
          int t = tG - 3 + i;
          if (t >= 0) {
            const __bf16* p = qpre + ((size_t)(b * TT + t)) * DD + h * DKd + cg * 16;
            tp0[i] = *(const bf16x8*)p; tp1[i] = *(const bf16x8*)(p + 8);
          } else { tp0[i] = z8; tp1[i] = z8; }
        }
        float ss = 0.f;
#pragma unroll
        for (int c = 0; c < 16; ++c) {
          const float4 w4 = *(const float4*)&cwkq[128 + cg * 16 + c][0];
          const int j = c & 7;
          float y = (c < 8)
              ? (w4.x * (float)tp0[0][j] + w4.y * (float)tp0[1][j] + w4.z * (float)tp0[2][j] + w4.w * (float)tp0[3][j])
              : (w4.x * (float)tp1[0][j] + w4.y * (float)tp1[1][j] + w4.z * (float)tp1[2][j] + w4.w * (float)tp1[3][j]);
          y = y * sigm(y);
          ss += y * y;
          __bf16 hi, lo; split2(y, hi, lo);
          Qhi[r][cg * 16 + c] = hi; Qlo[r][cg * 16 + c] = lo;
        }
        ss += __shfl_xor(ss, 1, 64); ss += __shfl_xor(ss, 2, 64); ss += __shfl_xor(ss, 4, 64);
        const float inv = rsqrtf(ss + 1e-6f) * 0.08838834764831845f;  // * DK^-0.5
#pragma unroll
        for (int c = 0; c < 16; ++c) {
          float v = ((float)Qhi[r][cg * 16 + c] + (float)Qlo[r][cg * 16 + c]) * inv;
          __bf16 hi, lo; split2(v, hi, lo);
          Qhi[r][cg * 16 + c] = hi; Qlo[r][cg * 16 + c] = lo;
        }
      }
      // ---- V (into RHSb, f32) ----
      {
        bf16x8 tv[4];
#pragma unroll
        for (int i = 0; i < 4; ++i) {
          int t = tG - 3 + i;
          tv[i] = (t >= 0) ? *(const bf16x8*)(vpre + ((size_t)(b * TT + t)) * K2 + h * DVd + jq * 64 + cg * 8) : z8;
        }
#pragma unroll
        for (int c = 0; c < 8; ++c) {
          const float4 w4 = *(const float4*)&cwv[cg * 8 + c][0];
          float y = w4.x * (float)tv[0][c] + w4.y * (float)tv[1][c] + w4.z * (float)tv[2][c] + w4.w * (float)tv[3][c];
          RHSb[r][cg * 8 + c] = y * sigm(y);
        }
      }
      // ---- decay scan + beta ----
      if (tid < 32) {
        float gv = g[gbase + t0 + tid];
        float bv = bet[gbase + t0 + tid];
        float cum = gv;
#pragma unroll
        for (int off = 1; off < 32; off <<= 1) {
          int src = (lane >= off) ? lane - off : lane;
          float n = __shfl(cum, src, 64);
          if (lane >= off) cum += n;
        }
        float LC = __shfl(cum, 31, 64);
        Lv[tid] = cum;
        Bv[tid] = bv;
        float eb = __expf(cum);
        Bb2[tid] = eb;
        BBv[tid] = bv * eb;
        BCb[tid] = __expf(LC - cum);
      }
    }
    __syncthreads();   // B0

    // ================= stage 1: A = mask(beta*exp(dL)*KK^T), P = mask(exp(dL)*QK^T)
    {
      const int tr = w >> 1, tc = w & 1;
      f32x4 accA = {0.f, 0.f, 0.f, 0.f}, accP = {0.f, 0.f, 0.f, 0.f};
#pragma unroll
      for (int kb = 0; kb < 128; kb += 32) {
        bf16x8 bh_ = *(const bf16x8*)&Khi[tc * 16 + r16][kb + g2 * 8];
        bf16x8 bl_ = *(const bf16x8*)&Klo[tc * 16 + r16][kb + g2 * 8];
        bf16x8 ah = *(const bf16x8*)&Khi[tr * 16 + r16][kb + g2 * 8];
        bf16x8 al = *(const bf16x8*)&Klo[tr * 16 + r16][kb + g2 * 8];
        accA = mfma3(ah, al, bh_, bl_, accA);
        bf16x8 qh = *(const bf16x8*)&Qhi[tr * 16 + r16][kb + g2 * 8];
        bf16x8 ql = *(const bf16x8*)&Qlo[tr * 16 + r16][kb + g2 * 8];
        accP = mfma3(qh, ql, bh_, bl_, accP);
      }
      const int jj = tc * 16 + r16;
      const float Lj = Lv[jj];
#pragma unroll
      for (int reg = 0; reg < 4; ++reg) {
        const int tt = tr * 16 + g2 * 4 + reg;
        const float dL = Lv[tt] - Lj;
        const float ex = __expf(dL);
        float av = (jj < tt) ? Bv[tt] * ex * accA[reg] : 0.f;
        float pv = (jj <= tt) ? ex * accP[reg] : 0.f;
        __bf16 hi, lo;
        split2(av, hi, lo); Ahi[tt][jj] = hi; Alo[tt][jj] = lo;
        split2(pv, hi, lo); Phi[tt][jj] = hi; Plo[tt][jj] = lo;
      }
    }
    __syncthreads();   // B1

    // ================= stage 2a: RHS = beta*V - diag(beta*b) K S0 =============
    {
      const int rb = w >> 1, cbs = (w & 1) * 2;
      f32x4 acc[2];
#pragma unroll
      for (int ct = 0; ct < 2; ++ct) {
        const int cc = (cbs + ct) * 16 + r16;
#pragma unroll
        for (int reg = 0; reg < 4; ++reg) {
          const int tt = rb * 16 + g2 * 4 + reg;
          acc[ct][reg] = Bv[tt] * RHSb[tt][cc];
        }
      }
      const float fneg = -BBv[rb * 16 + r16];
#pragma unroll
      for (int kb = 0; kb < 128; kb += 32) {
        bf16x8 xh = *(const bf16x8*)&Khi[rb * 16 + r16][kb + g2 * 8];
        bf16x8 xl = *(const bf16x8*)&Klo[rb * 16 + r16][kb + g2 * 8];
        bf16x8 ah, al;
#pragma unroll
        for (int j = 0; j < 8; ++j) {
          float v = fneg * ((float)xh[j] + (float)xl[j]);
          __bf16 hi, lo; split2(v, hi, lo); ah[j] = hi; al[j] = lo;
        }
#pragma unroll
        for (int ct = 0; ct < 2; ++ct) {
          bf16x8 sh = *(const bf16x8*)&SThi[(cbs + ct) * 16 + r16][kb + g2 * 8];
          bf16x8 sl = *(const bf16x8*)&STlo[(cbs + ct) * 16 + r16][kb + g2 * 8];
          acc[ct] = mfma3(ah, al, sh, sl, acc[ct]);
        }
      }
#pragma unroll
      for (int ct = 0; ct < 2; ++ct) {
        const int cc = (cbs + ct) * 16 + r16;
#pragma unroll
        for (int reg = 0; reg < 4; ++reg)
          RHSb[rb * 16 + g2 * 4 + reg][cc] = acc[ct][reg];
      }
    }
    // ---- T_I = (I+L)^{-1} = (I-L)(I+L2)(I+L4)(I+L8), waves 0,1 ----
    if (w < 2) {
      const int I = w, r0 = I * 16, s = I + 2;
      bf16x8 Lh_r = z8, Ll_r = z8, Lh_t = z8, Ll_t = z8;
      if (g2 < 2) {
        Lh_r = *(const bf16x8*)&Ahi[r0 + r16][r0 + g2 * 8];
        Ll_r = *(const bf16x8*)&Alo[r0 + r16][r0 + g2 * 8];
#pragma unroll
        for (int j = 0; j < 8; ++j) {
          Lh_t[j] = Ahi[r0 + g2 * 8 + j][r0 + r16];
          Ll_t[j] = Alo[r0 + g2 * 8 + j][r0 + r16];
        }
      }
      f32x4 acc = {0.f, 0.f, 0.f, 0.f};
      acc = mfma3(Lh_r, Ll_r, Lh_t, Ll_t, acc);                  // L2
#pragma unroll
      for (int reg = 0; reg < 4; ++reg) { __bf16 hi, lo; split2(acc[reg], hi, lo);
        Thi[s][g2 * 4 + reg][r16] = hi; Tlo[s][g2 * 4 + reg][r16] = lo; }
      // R1 = I - L + L2 - L*L2
      bf16x8 L2h_r = z8, L2l_r = z8, L2h_t = z8, L2l_t = z8;
      if (g2 < 2) { L2h_r = *(const bf16x8*)&Thi[s][r16][g2 * 8]; L2l_r = *(const bf16x8*)&Tlo[s][r16][g2 * 8]; }
#pragma unroll
      for (int j = 0; j < 8; ++j) if (g2 < 2) { L2h_t[j] = Thi[s][g2 * 8 + j][r16]; L2l_t[j] = Tlo[s][g2 * 8 + j][r16]; }
      bf16x8 nLh = Lh_r, nLl = Ll_r;
#pragma unroll
      for (int j = 0; j < 8; ++j) { nLh[j] = -nLh[j]; nLl[j] = -nLl[j]; }
      f32x4 accR;
#pragma unroll
      for (int reg = 0; reg < 4; ++reg) {
        const int rr = g2 * 4 + reg;
        float lw = (float)Ahi[r0 + rr][r0 + r16] + (float)Alo[r0 + rr][r0 + r16];
        float l2w = (float)Thi[s][rr][r16] + (float)Tlo[s][rr][r16];
        accR[reg] = ((rr == r16) ? 1.f : 0.f) - lw + l2w;
      }
      accR = mfma3(nLh, nLl, L2h_t, L2l_t, accR);
#pragma unroll
      for (int reg = 0; reg < 4; ++reg) { __bf16 hi, lo; split2(accR[reg], hi, lo);
        Thi[I][g2 * 4 + reg][r16] = hi; Tlo[I][g2 * 4 + reg][r16] = lo; }
      // L4 = L2*L2
      f32x4 acc4 = {0.f, 0.f, 0.f, 0.f};
      acc4 = mfma3(L2h_r, L2l_r, L2h_t, L2l_t, acc4);
#pragma unroll
      for (int reg = 0; reg < 4; ++reg) { __bf16 hi, lo; split2(acc4[reg], hi, lo);
        Thi[s][g2 * 4 + reg][r16] = hi; Tlo[s][g2 * 4 + reg][r16] = lo; }
      // R2 = R1 + R1*L4
      bf16x8 R1h_r = z8, R1l_r = z8, L4h_t = z8, L4l_t = z8, L4h_r = z8, L4l_r = z8;
      if (g2 < 2) {
        R1h_r = *(const bf16x8*)&Thi[I][r16][g2 * 8]; R1l_r = *(const bf16x8*)&Tlo[I][r16][g2 * 8];
        L4h_r = *(const bf16x8*)&Thi[s][r16][g2 * 8]; L4l_r = *(const bf16x8*)&Tlo[s][r16][g2 * 8];
#pragma unroll
        for (int j = 0; j < 8; ++j) { L4h_t[j] = Thi[s][g2 * 8 + j][r16]; L4l_t[j] = Tlo[s][g2 * 8 + j][r16]; }
      }
      f32x4 accR2;
#pragma unroll
      for (int reg = 0; reg < 4; ++reg)
        accR2[reg] = (float)Thi[I][g2 * 4 + reg][r16] + (float)Tlo[I][g2 * 4 + reg][r16];
      accR2 = mfma3(R1h_r, R1l_r, L4h_t, L4l_t, accR2);
#pragma unroll
      for (int reg = 0; reg < 4; ++reg) { __bf16 hi, lo; split2(accR2[reg], hi, lo);
        Thi[I][g2 * 4 + reg][r16] = hi; Tlo[I][g2 * 4 + reg][r16] = lo; }
      // L8 = L4*L4
      f32x4 acc8 = {0.f, 0.f, 0.f, 0.f};
      acc8 = mfma3(L4h_r, L4l_r, L4h_t, L4l_t, acc8);
#pragma unroll
      for (int reg = 0; reg < 4; ++reg) { __bf16 hi, lo; split2(acc8[reg], hi, lo);
        Thi[s][g2 * 4 + reg][r16] = hi; Tlo[s][g2 * 4 + reg][r16] = lo; }
      // T = R2 + R2*L8
      bf16x8 R2h_r = z8, R2l_r = z8, L8h_t = z8, L8l_t = z8;
      if (g2 < 2) {
        R2h_r = *(const bf16x8*)&Thi[I][r16][g2 * 8]; R2l_r = *(const bf16x8*)&Tlo[I][r16][g2 * 8];
#pragma unroll
        for (int j = 0; j < 8; ++j) { L8h_t[j] = Thi[s][g2 * 8 + j][r16]; L8l_t[j] = Tlo[s][g2 * 8 + j][r16]; }
      }
      f32x4 accT;
#pragma unroll
      for (int reg = 0; reg < 4; ++reg)
        accT[reg] = (float)Thi[I][g2 * 4 + reg][r16] + (float)Tlo[I][g2 * 4 + reg][r16];
      accT = mfma3(R2h_r, R2l_r, L8h_t, L8l_t, accT);
#pragma unroll
      for (int reg = 0; reg < 4; ++reg) { __bf16 hi, lo; split2(accT[reg], hi, lo);
        Thi[I][g2 * 4 + reg][r16] = hi; Tlo[I][g2 * 4 + reg][r16] = lo; }
    }
    __syncthreads();   // B2

    // ================= stage 2b: blocked forward substitution ================
    // GT <- RHS rows 0..15
    {
      const int id0 = tid * 4;
      const int t = id0 >> 6, c0 = id0 & 63;
#pragma unroll
      for (int i = 0; i < 4; ++i) {
        __bf16 hi, lo; split2(RHSb[t][c0 + i], hi, lo);
        GThi[c0 + i][t] = hi; GTlo[c0 + i][t] = lo;
      }
    }
    __syncthreads();   // B3
    // V'_0 = T_0 * G
    {
      bf16x8 th = z8, tl = z8, gh = z8, gl = z8;
      if (g2 < 2) {
        th = *(const bf16x8*)&Thi[0][r16][g2 * 8]; tl = *(const bf16x8*)&Tlo[0][r16][g2 * 8];
        gh = *(const bf16x8*)&GThi[w * 16 + r16][g2 * 8]; gl = *(const bf16x8*)&GTlo[w * 16 + r16][g2 * 8];
      }
      f32x4 acc = {0.f, 0.f, 0.f, 0.f};
      acc = mfma3(th, tl, gh, gl, acc);
      bf16x4 p4h, p4l;
#pragma unroll
      for (int reg = 0; reg < 4; ++reg) { __bf16 hi, lo; split2(acc[reg], hi, lo); p4h[reg] = hi; p4l[reg] = lo; }
      *(bf16x4*)&VThi[w * 16 + r16][g2 * 4] = p4h;
      *(bf16x4*)&VTlo[w * 16 + r16][g2 * 4] = p4l;
    }
    __syncthreads();   // B4
    // G = RHS rows 16..31 - A_10 V'_0
    {
      const int cb = w;
      f32x4 acc;
#pragma unroll
      for (int reg = 0; reg < 4; ++reg) acc[reg] = RHSb[16 + g2 * 4 + reg][cb * 16 + r16];
      bf16x8 ah = z8, al = z8, vh = z8, vl = z8;
      if (g2 < 2) {
        ah = *(const bf16x8*)&Ahi[16 + r16][g2 * 8]; al = *(const bf16x8*)&Alo[16 + r16][g2 * 8];
#pragma unroll
        for (int j = 0; j < 8; ++j) { ah[j] = -ah[j]; al[j] = -al[j]; }
        vh = *(const bf16x8*)&VThi[cb * 16 + r16][g2 * 8]; vl = *(const bf16x8*)&VTlo[cb * 16 + r16][g2 * 8];
      }
      acc = mfma3(ah, al, vh, vl, acc);
      bf16x4 p4h, p4l;
#pragma unroll
      for (int reg = 0; reg < 4; ++reg) { __bf16 hi, lo; split2(acc[reg], hi, lo); p4h[reg] = hi; p4l[reg] = lo; }
      *(bf16x4*)&GThi[cb * 16 + r16][g2 * 4] = p4h;
      *(bf16x4*)&GTlo[cb * 16 + r16][g2 * 4] = p4l;
    }
    __syncthreads();   // B5
    // V'_1 = T_1 * G
    {
      bf16x8 th = z8, tl = z8, gh = z8, gl = z8;
      if (g2 < 2) {
        th = *(const bf16x8*)&Thi[1][r16][g2 * 8]; tl = *(const bf16x8*)&Tlo[1][r16][g2 * 8];
        gh = *(const bf16x8*)&GThi[w * 16 + r16][g2 * 8]; gl = *(const bf16x8*)&GTlo[w * 16 + r16][g2 * 8];
      }
      f32x4 acc = {0.f, 0.f, 0.f, 0.f};
      acc = mfma3(th, tl, gh, gl, acc);
      bf16x4 p4h, p4l;
#pragma unroll
      for (int reg = 0; reg < 4; ++reg) { __bf16 hi, lo; split2(acc[reg], hi, lo); p4h[reg] = hi; p4l[reg] = lo; }
      *(bf16x4*)&VThi[w * 16 + r16][16 + g2 * 4] = p4h;
      *(bf16x4*)&VTlo[w * 16 + r16][16 + g2 * 4] = p4l;
    }
    __syncthreads();   // B6

    // ================= stage 3a: O = diag(b)Q S0 + P V' =======================
    {
      const int rb = w >> 1, cbs = (w & 1) * 2;
      f32x4 acc[2] = {{0.f, 0.f, 0.f, 0.f}, {0.f, 0.f, 0.f, 0.f}};
      const float fq = Bb2[rb * 16 + r16];
#pragma unroll
      for (int kb = 0; kb < 128; kb += 32) {
        bf16x8 xh = *(const bf16x8*)&Qhi[rb * 16 + r16][kb + g2 * 8];
        bf16x8 xl = *(const bf16x8*)&Qlo[rb * 16 + r16][kb + g2 * 8];
        bf16x8 qh, ql;
#pragma unroll
        for (int j = 0; j < 8; ++j) {
          float v = fq * ((float)xh[j] + (float)xl[j]);
          __bf16 hi, lo; split2(v, hi, lo); qh[j] = hi; ql[j] = lo;
        }
#pragma unroll
        for (int ct = 0; ct < 2; ++ct) {
          bf16x8 sh = *(const bf16x8*)&SThi[(cbs + ct) * 16 + r16][kb + g2 * 8];
          bf16x8 sl = *(const bf16x8*)&STlo[(cbs + ct) * 16 + r16][kb + g2 * 8];
          acc[ct] = mfma3(qh, ql, sh, sl, acc[ct]);
        }
      }
      bf16x8 ph = *(const bf16x8*)&Phi[rb * 16 + r16][g2 * 8];
      bf16x8 pl = *(const bf16x8*)&Plo[rb * 16 + r16][g2 * 8];
#pragma unroll
      for (int ct = 0; ct < 2; ++ct) {
        bf16x8 vh = *(const bf16x8*)&VThi[(cbs + ct) * 16 + r16][g2 * 8];
        bf16x8 vl = *(const bf16x8*)&VTlo[(cbs + ct) * 16 + r16][g2 * 8];
        acc[ct] = mfma3(ph, pl, vh, vl, acc[ct]);
        const int cc = (cbs + ct) * 16 + r16;
#pragma unroll
        for (int reg = 0; reg < 4; ++reg) {
          const int tt = rb * 16 + g2 * 4 + reg;
          o[obase + (size_t)(t0 + tt) * DVd + cc] = (__bf16)acc[ct][reg];
        }
      }
    }
    __syncthreads();   // B7

    // ================= stage 3b: S = bC*S0 + Khat^T V' ========================
    {
      const float bCf = __expf(Lv[31]);
      bf16x8 vh4[4], vl4[4];
#pragma unroll
      for (int cb = 0; cb < 4; ++cb) {
        vh4[cb] = *(const bf16x8*)&VThi[cb * 16 + r16][g2 * 8];
        vl4[cb] = *(const bf16x8*)&VTlo[cb * 16 + r16][g2 * 8];
      }
#pragma unroll
      for (int rr = 0; rr < 2; ++rr) {
        const int rb = w * 2 + rr, d0 = rb * 16;
        bf16x8 kh, kl;
#pragma unroll
        for (int j = 0; j < 8; ++j) {
          const int t = g2 * 8 + j;
          float v = BCb[t] * ((float)Khi[t][d0 + r16] + (float)Klo[t][d0 + r16]);
          __bf16 hi, lo; split2(v, hi, lo); kh[j] = hi; kl[j] = lo;
        }
#pragma unroll
        for (int cb = 0; cb < 4; ++cb) {
          f32x4 acc;
          const int cc = cb * 16 + r16;
#pragma unroll
          for (int reg = 0; reg < 4; ++reg) {
            const int dd = d0 + g2 * 4 + reg;
            acc[reg] = bCf * ((float)SThi[cc][dd] + (float)STlo[cc][dd]);
          }
          acc = mfma3(kh, kl, vh4[cb], vl4[cb], acc);
          bf16x4 p4h, p4l;
#pragma unroll
          for (int reg = 0; reg < 4; ++reg) { __bf16 hi, lo; split2(acc[reg], hi, lo); p4h[reg] = hi; p4l[reg] = lo; }
          *(bf16x4*)&SThi[cc][d0 + g2 * 4] = p4h;
          *(bf16x4*)&STlo[cc][d0 + g2 * 4] = p4l;
        }
      }
    }
    __syncthreads();   // B8 (end of chunk)
  }
}

// ---------------- gated RMSNorm epilogue + split-bf16 of o ----------------
__global__ void epilogue_kernel(const __bf16* __restrict__ o, const __bf16* __restrict__ gate,
                                const float* __restrict__ wn, __bf16* __restrict__ Os)
{
  const int bid = blockIdx.x;          // m*H + h
  const int m = bid / HH, h = bid - m * HH;
  const int b = m >> 11, t = m & (TT - 1);
  const int j = threadIdx.x;
  const float ov = (float)o[((size_t)(b * HH + h) * TT + t) * DVd + j];
  float ss = ov * ov;
#pragma unroll
  for (int off = 32; off; off >>= 1) ss += __shfl_xor(ss, off, 64);
  __shared__ float red[4];
  if ((j & 63) == 0) red[j >> 6] = ss;
  __syncthreads();
  const float inv = rsqrtf((red[0] + red[1] + red[2] + red[3]) * (1.f / DVd) + 1e-5f);
  const float gt = (float)gate[(size_t)m * K2 + h * DVd + j];
  const float val = ov * inv * wn[j] * (gt * sigm(gt));
  const __bf16 hi = (__bf16)val;
  const __bf16 lo = (__bf16)(val - (float)hi);
  const size_t ob = (size_t)m * (2 * K2) + h * DVd + j;
  Os[ob] = hi; Os[ob + K2] = lo;
}

// ---------------- ws-too-small sentinel ----------------
__global__ void sentinel_kernel(float* __restrict__ out, float val) {
  out[threadIdx.x] = val;
}

// ---------------- launch ----------------
extern "C" void kernel_launch(void* const* d_in, const int* in_sizes, int n_in,
                              void* d_out, int out_size, void* d_ws, size_t ws_size,
                              hipStream_t stream) {
  const float* x    = (const float*)d_in[0];
  const float* Wq   = (const float*)d_in[1];
  const float* Wk   = (const float*)d_in[2];
  const float* Wv   = (const float*)d_in[3];
  const float* Wa   = (const float*)d_in[4];
  const float* Wb   = (const float*)d_in[5];
  const float* Wg   = (const float*)d_in[6];
  const float* Wo   = (const float*)d_in[7];
  const float* cq   = (const float*)d_in[8];
  const float* ck   = (const float*)d_in[9];
  const float* cv   = (const float*)d_in[10];
  const float* Alog = (const float*)d_in[11];
  const float* dtb  = (const float*)d_in[12];
  const float* onw  = (const float*)d_in[13];
  float* out = (float*)d_out;
  uint8_t* ws = (uint8_t*)d_ws;

  // ---- workspace layout (bytes); lifetime-aliased. peak = 230,424,576 ----
  const size_t oGt = 0;                    // gate bf16 [16384,1536]   50,331,648
  const size_t oG  = oGt + 50331648;       // g f32 [48,2048]             393,216
  const size_t oBt = oG  + 393216;         // beta f32                    393,216
  const size_t oWo = oBt + 393216;         // Wo' bf16 [768,4608]       7,077,888
  const size_t oWq = oWo + 7077888;        // Wq' bf16 [768,2304]       3,538,944
  const size_t oWk = oWq + 3538944;
  const size_t oWv = oWk + 3538944;        // Wv' bf16 [1536,2304]      7,077,888
  const size_t oWg = oWv + 7077888;
  const size_t oXs = oWg + 7077888;        // Xs bf16 [16384,1536]     50,331,648
  const size_t oQp = oXs + 50331648;       // qpre bf16 [16384,768]    25,165,824
  const size_t oKp = oQp + 25165824;
  const size_t oVp = oKp + 25165824;       // vpre bf16 [16384,1536]   50,331,648
  const size_t total = oVp + 50331648;     // 230,424,576
  const size_t oO  = oXs;                  // o bf16 over Xs (dead after GEMMs)
  const size_t oOs = oQp;                  // Os bf16 over pre bufs (dead after delta)

  if (ws_size < total) {
    sentinel_kernel<<<1, 256, 0, stream>>>(out, 1.0e7f + (float)(ws_size >> 20));
    return;
  }

  __bf16* Xs   = (__bf16*)(ws + oXs);
  __bf16* Wqp  = (__bf16*)(ws + oWq);
  __bf16* Wkp  = (__bf16*)(ws + oWk);
  __bf16* Wvp  = (__bf16*)(ws + oWv);
  __bf16* Wgp  = (__bf16*)(ws + oWg);
  __bf16* Wop  = (__bf16*)(ws + oWo);
  __bf16* qpre = (__bf16*)(ws + oQp);
  __bf16* kpre = (__bf16*)(ws + oKp);
  __bf16* vpre = (__bf16*)(ws + oVp);
  __bf16* gate = (__bf16*)(ws + oGt);
  float*  gbuf = (float*)(ws + oG);
  float*  bbuf = (float*)(ws + oBt);
  __bf16* oBuf = (__bf16*)(ws + oO);
  __bf16* Os   = (__bf16*)(ws + oOs);

  // phase A: conversions + projections
  convert_x_kernel<<<MM * DD / 256, 256, 0, stream>>>(x, Xs);
  convert_w_kernel<<<768 * 3 * K1 / 256, 256, 0, stream>>>(Wq, Wqp, K1, 768);
  convert_w_kernel<<<768 * 3 * K1 / 256, 256, 0, stream>>>(Wk, Wkp, K1, 768);
  convert_w_kernel<<<1536 * 3 * K1 / 256, 256, 0, stream>>>(Wv, Wvp, K1, 1536);
  convert_w_kernel<<<1536 * 3 * K1 / 256, 256, 0, stream>>>(Wg, Wgp, K1, 1536);
  convert_w_kernel<<<768 * 3 * K2 / 256, 256, 0, stream>>>(Wo, Wop, K2, 768);
  gemm_split<__bf16><<<dim3(128, 6),  256, 0, stream>>>(Xs, Wqp, qpre, 768,  K1);
  gemm_split<__bf16><<<dim3(128, 6),  256, 0, stream>>>(Xs, Wkp, kpre, 768,  K1);
  gemm_split<__bf16><<<dim3(128, 12), 256, 0, stream>>>(Xs, Wvp, vpre, 1536, K1);
  gemm_split<__bf16><<<dim3(128, 12), 256, 0, stream>>>(Xs, Wgp, gate, 1536, K1);
  gb_kernel<<<MM / 4, 256, 0, stream>>>(x, Wa, Wb, Alog, dtb, gbuf, bbuf);
  // phase C: chunked gated delta rule (conv/silu/l2norm fused)
  delta_kernel<<<dim3(BB * HH, 4), 256, 0, stream>>>(qpre, kpre, vpre, cq, ck, cv,
                                                     gbuf, bbuf, oBuf);
  // phase D: gated RMSNorm + split-bf16, final projection
  epilogue_kernel<<<MM * HH, 256, 0, stream>>>(oBuf, gate, onw, Os);
  gemm_split<float><<<dim3(128, 6), 256, 0, stream>>>(Os, Wop, out, 768, K2);
}

// Round 6
// 1639.496 us; speedup vs baseline: 2.4365x; 1.0691x over previous
//
#include <hip/hip_runtime.h>
#include <hip/hip_bf16.h>
#include <stdint.h>

// ---------------- geometry ----------------
#define BB   8
#define TT   2048
#define DD   768
#define HH   6
#define DKd  128
#define DVd  256
#define MM   (BB*TT)      // 16384 rows
#define K1   768
#define K2   1536
#define CC   32           // delta chunk length

typedef __bf16 bf16x8 __attribute__((ext_vector_type(8)));
typedef __bf16 bf16x4 __attribute__((ext_vector_type(4)));
typedef float  f32x4  __attribute__((ext_vector_type(4)));

__device__ __forceinline__ float sigm(float x) { return 1.f / (1.f + __expf(-x)); }
__device__ __forceinline__ void split2(float v, __bf16& hi, __bf16& lo) {
  hi = (__bf16)v; lo = (__bf16)(v - (float)hi);
}
__device__ __forceinline__ f32x4 mfma3(bf16x8 ah, bf16x8 al, bf16x8 bh_, bf16x8 bl_, f32x4 acc) {
  acc = __builtin_amdgcn_mfma_f32_16x16x32_bf16(ah, bh_, acc, 0, 0, 0);
  acc = __builtin_amdgcn_mfma_f32_16x16x32_bf16(ah, bl_, acc, 0, 0, 0);
  acc = __builtin_amdgcn_mfma_f32_16x16x32_bf16(al, bh_, acc, 0, 0, 0);
  return acc;
}

// ---------------- f32 -> split-bf16 conversions ----------------
__global__ void convert_x_kernel(const float* __restrict__ x, __bf16* __restrict__ Xs) {
  int idx = blockIdx.x * 256 + threadIdx.x;
  if (idx >= MM * DD) return;
  int m = idx / DD, c = idx - m * DD;
  float v = x[idx];
  __bf16 h = (__bf16)v;
  __bf16 l = (__bf16)(v - (float)h);
  size_t base = (size_t)m * (2 * K1) + c;
  Xs[base] = h; Xs[base + K1] = l;
}

__global__ void convert_w_kernel(const float* __restrict__ W, __bf16* __restrict__ Wt,
                                 int K, int N) {
  int idx = blockIdx.x * 256 + threadIdx.x;
  if (idx >= N * 3 * K) return;
  int n = idx / (3 * K), kk = idx - n * (3 * K);
  int blk = kk / K, k = kk - blk * K;
  float v = W[(size_t)k * N + n];
  __bf16 h = (__bf16)v;
  Wt[idx] = (blk == 1) ? (__bf16)(v - (float)h) : h;
}

// ---------------- bf16 MFMA GEMM: C[M,N] = A'[M,3K] * Bt[N,3K]^T ----------------
template <typename OutT>
__global__ __launch_bounds__(256) void gemm_split(
    const __bf16* __restrict__ A, const __bf16* __restrict__ Bt,
    OutT* __restrict__ C, int N, int Khi)
{
  __shared__ __bf16 Als[128 * 32];
  __shared__ __bf16 Bls[128 * 32];
  const int LDA = 2 * Khi, Klog = 3 * Khi;
  const int tid = threadIdx.x;
  const int lane = tid & 63, w = tid >> 6;
  const int wr = w >> 1, wc = w & 1;
  const int bm = blockIdx.x, bn = blockIdx.y;
  f32x4 acc[4][4] = {};
  const __bf16* Ab = A + (size_t)bm * 128 * LDA;
  const __bf16* Bb = Bt + (size_t)bn * 128 * Klog;
  const int r0 = tid >> 2, co0 = (tid & 3) * 8;
  const int r1 = (256 + tid) >> 2, co1 = ((256 + tid) & 3) * 8;
  for (int k0 = 0; k0 < Klog; k0 += 32) {
    const int kc = (k0 < Khi) ? k0 : k0 - Khi;
    __syncthreads();
    __builtin_amdgcn_global_load_lds(
        (const __attribute__((address_space(1))) void*)(Ab + (size_t)r0 * LDA + kc + co0),
        (__attribute__((address_space(3))) void*)(Als + (w * 64) * 8), 16, 0, 0);
    __builtin_amdgcn_global_load_lds(
        (const __attribute__((address_space(1))) void*)(Ab + (size_t)r1 * LDA + kc + co1),
        (__attribute__((address_space(3))) void*)(Als + (256 + w * 64) * 8), 16, 0, 0);
    __builtin_amdgcn_global_load_lds(
        (const __attribute__((address_space(1))) void*)(Bb + (size_t)r0 * Klog + k0 + co0),
        (__attribute__((address_space(3))) void*)(Bls + (w * 64) * 8), 16, 0, 0);
    __builtin_amdgcn_global_load_lds(
        (const __attribute__((address_space(1))) void*)(Bb + (size_t)r1 * Klog + k0 + co1),
        (__attribute__((address_space(3))) void*)(Bls + (256 + w * 64) * 8), 16, 0, 0);
    __syncthreads();
    bf16x8 af[4], bfr[4];
    const int rb = wr * 64 + (lane & 15);
    const int kb = (lane >> 4) * 8;
#pragma unroll
    for (int i = 0; i < 4; ++i) af[i] = *(const bf16x8*)(Als + (rb + i * 16) * 32 + kb);
    const int cb = wc * 64 + (lane & 15);
#pragma unroll
    for (int i = 0; i < 4; ++i) bfr[i] = *(const bf16x8*)(Bls + (cb + i * 16) * 32 + kb);
#pragma unroll
    for (int mi = 0; mi < 4; ++mi)
#pragma unroll
      for (int ni = 0; ni < 4; ++ni)
        acc[mi][ni] = __builtin_amdgcn_mfma_f32_16x16x32_bf16(af[mi], bfr[ni], acc[mi][ni], 0, 0, 0);
  }
  const int row0 = bm * 128 + wr * 64;
  const int col0 = bn * 128 + wc * 64 + (lane & 15);
  const int rsub = (lane >> 4) * 4;
#pragma unroll
  for (int mi = 0; mi < 4; ++mi)
#pragma unroll
    for (int ni = 0; ni < 4; ++ni)
#pragma unroll
      for (int r = 0; r < 4; ++r) {
        int row = row0 + mi * 16 + rsub + r;
        C[(size_t)row * N + col0 + ni * 16] = (OutT)acc[mi][ni][r];
      }
}

// ---------------- g / beta projections ----------------
__global__ void gb_kernel(const float* __restrict__ x, const float* __restrict__ Wa,
                          const float* __restrict__ Wb, const float* __restrict__ A_log,
                          const float* __restrict__ dt_bias, float* __restrict__ g,
                          float* __restrict__ bet)
{
  const int row = blockIdx.x * 4 + (threadIdx.x >> 6);
  const int lane = threadIdx.x & 63;
  float aA[6] = {0, 0, 0, 0, 0, 0}, aB[6] = {0, 0, 0, 0, 0, 0};
  const float* xr = x + (size_t)row * DD;
  for (int kk = 0; kk < 12; ++kk) {
    const int c = lane + kk * 64;
    const float xv = xr[c];
#pragma unroll
    for (int hh = 0; hh < 6; ++hh) { aA[hh] += xv * Wa[c * 6 + hh]; aB[hh] += xv * Wb[c * 6 + hh]; }
  }
#pragma unroll
  for (int hh = 0; hh < 6; ++hh) {
#pragma unroll
    for (int off = 32; off; off >>= 1) {
      aA[hh] += __shfl_xor(aA[hh], off, 64);
      aB[hh] += __shfl_xor(aB[hh], off, 64);
    }
  }
  if (lane == 0) {
    const int b = row >> 11, t = row & (TT - 1);
#pragma unroll
    for (int hh = 0; hh < 6; ++hh) {
      const float a = aA[hh] + dt_bias[hh];
      const float sp = (a > 20.f) ? a : log1pf(__expf(a));
      const size_t gi = ((size_t)(b * HH + hh)) * TT + t;
      g[gi] = -__expf(A_log[hh]) * sp;
      bet[gi] = 1.f / (1.f + __expf(-aB[hh]));
    }
  }
}

// ---------------- chunked gated delta rule v3 ----------------
// grid (48,4): (b*H+h, DV-quarter). 256 thr = 4 waves. Chunks CC=32.
// Raw (unnormalized) K,Q stored hi/lo via vector writes; l2norm factors ivk/ivq
// folded exactly into f32 epilogues. 7 barriers/chunk. Parallel V' solve via
// precomputed M = T1*A10*T0 (written negated).
__global__ __launch_bounds__(256) void delta_kernel(
    const __bf16* __restrict__ qpre, const __bf16* __restrict__ kpre,
    const __bf16* __restrict__ vpre,
    const float* __restrict__ cq, const float* __restrict__ ck,
    const float* __restrict__ cv,
    const float* __restrict__ g, const float* __restrict__ bet,
    __bf16* __restrict__ o)
{
  const int bh = blockIdx.x, b = bh / HH, h = bh - b * HH;
  const int jq = blockIdx.y;
  const int tid = threadIdx.x, lane = tid & 63, w = tid >> 6;
  const int r16 = lane & 15, g2 = lane >> 4;

  __shared__ __align__(16) __bf16 Khi[32][136], Klo[32][136];     // raw conv+silu K
  __shared__ __align__(16) __bf16 Qhi[32][136], Qlo[32][136];     // raw conv+silu Q
  __shared__ __align__(16) __bf16 SThi[64][136], STlo[64][136];   // S^T [c][d]
  __shared__ __align__(16) __bf16 Ahi[32][40],  Alo[32][40];
  __shared__ __align__(16) __bf16 Phi[32][40],  Plo[32][40];
  __shared__ __align__(16) __bf16 Athi[16][24], Atlo[16][24];     // A10^T
  __shared__ __align__(16) __bf16 VThi[64][40], VTlo[64][40];     // V'^T [c][t]
  __shared__ __align__(16) __bf16 V2hi[64][40], V2lo[64][40];     // V'^T scaled BCb*ivk
  __shared__ __align__(16) __bf16 GThi[64][40], GTlo[64][40];     // RHS^T [c][t]
  __shared__ __align__(16) __bf16 Thi[4][16][24], Tlo[4][16][24]; // 0,1=T; 2=T0^T; 3=X/scratch
  __shared__ __align__(16) __bf16 Mhi[16][24], Mlo[16][24];       // -T1*A10*T0
  __shared__ __align__(16) float  RHSb[32][68];                   // raw silu V (f32)
  __shared__ __align__(16) float  cwkq[256][4];
  __shared__ __align__(16) float  cwv[64][4];
  __shared__ float Lv[32], Bv[32], Bb2[32], BCb[32], ivk[32], ivq[32];

  // conv weights (k: rows 0..127, q: 128..255)
  {
    const float* src = (tid < 128) ? ck + (size_t)(h * DKd + tid) * 4
                                   : cq + (size_t)(h * DKd + (tid - 128)) * 4;
    *(float4*)&cwkq[tid][0] = *(const float4*)src;
    if (tid < 64) *(float4*)&cwv[tid][0] = *(const float4*)(cv + (size_t)(h * DVd + jq * 64 + tid) * 4);
  }
  // zero S^T
  for (int i = tid; i < 1088; i += 256) {
    ((uint4*)SThi)[i] = make_uint4(0, 0, 0, 0);
    ((uint4*)STlo)[i] = make_uint4(0, 0, 0, 0);
  }
  __syncthreads();

  const size_t gbase = (size_t)bh * TT;
  const size_t obase = (size_t)bh * TT * DVd + jq * 64;
  const bf16x8 z8 = {};

  for (int chk = 0; chk < TT / CC; ++chk) {
    const int t0 = chk * CC;
    // ================= stage 0: conv+silu (register path), scans =============
    {
      const int r = tid >> 3, cg = tid & 7;
      const int tG = t0 + r;
      bf16x8 kta[4], ktb[4], qta[4], qtb[4], vt4[4];
#pragma unroll
      for (int i = 0; i < 4; ++i) {
        const int t = tG - 3 + i;
        if (t >= 0) {
          const __bf16* pk = kpre + ((size_t)(b * TT + t)) * DD + h * DKd + cg * 16;
          kta[i] = *(const bf16x8*)pk; ktb[i] = *(const bf16x8*)(pk + 8);
          const __bf16* pq = qpre + ((size_t)(b * TT + t)) * DD + h * DKd + cg * 16;
          qta[i] = *(const bf16x8*)pq; qtb[i] = *(const bf16x8*)(pq + 8);
          vt4[i] = *(const bf16x8*)(vpre + ((size_t)(b * TT + t)) * K2 + h * DVd + jq * 64 + cg * 8);
        } else { kta[i] = z8; ktb[i] = z8; qta[i] = z8; qtb[i] = z8; vt4[i] = z8; }
      }
      // K
      {
        float y[16]; float ss = 0.f;
#pragma unroll
        for (int c = 0; c < 16; ++c) {
          const float4 w4 = *(const float4*)&cwkq[cg * 16 + c][0];
          const int j = c & 7;
          float v = (c < 8)
              ? (w4.x * (float)kta[0][j] + w4.y * (float)kta[1][j] + w4.z * (float)kta[2][j] + w4.w * (float)kta[3][j])
              : (w4.x * (float)ktb[0][j] + w4.y * (float)ktb[1][j] + w4.z * (float)ktb[2][j] + w4.w * (float)ktb[3][j]);
          v = v * sigm(v); y[c] = v; ss += v * v;
        }
        ss += __shfl_xor(ss, 1, 64); ss += __shfl_xor(ss, 2, 64); ss += __shfl_xor(ss, 4, 64);
        if (cg == 0) ivk[r] = rsqrtf(ss + 1e-6f);
        bf16x8 h8, l8;
#pragma unroll
        for (int j = 0; j < 8; ++j) { __bf16 hi, lo; split2(y[j], hi, lo); h8[j] = hi; l8[j] = lo; }
        *(bf16x8*)&Khi[r][cg * 16] = h8; *(bf16x8*)&Klo[r][cg * 16] = l8;
#pragma unroll
        for (int j = 0; j < 8; ++j) { __bf16 hi, lo; split2(y[8 + j], hi, lo); h8[j] = hi; l8[j] = lo; }
        *(bf16x8*)&Khi[r][cg * 16 + 8] = h8; *(bf16x8*)&Klo[r][cg * 16 + 8] = l8;
      }
      // Q (ivq includes DK^-0.5)
      {
        float y[16]; float ss = 0.f;
#pragma unroll
        for (int c = 0; c < 16; ++c) {
          const float4 w4 = *(const float4*)&cwkq[128 + cg * 16 + c][0];
          const int j = c & 7;
          float v = (c < 8)
              ? (w4.x * (float)qta[0][j] + w4.y * (float)qta[1][j] + w4.z * (float)qta[2][j] + w4.w * (float)qta[3][j])
              : (w4.x * (float)qtb[0][j] + w4.y * (float)qtb[1][j] + w4.z * (float)qtb[2][j] + w4.w * (float)qtb[3][j]);
          v = v * sigm(v); y[c] = v; ss += v * v;
        }
        ss += __shfl_xor(ss, 1, 64); ss += __shfl_xor(ss, 2, 64); ss += __shfl_xor(ss, 4, 64);
        if (cg == 0) ivq[r] = rsqrtf(ss + 1e-6f) * 0.08838834764831845f;
        bf16x8 h8, l8;
#pragma unroll
        for (int j = 0; j < 8; ++j) { __bf16 hi, lo; split2(y[j], hi, lo); h8[j] = hi; l8[j] = lo; }
        *(bf16x8*)&Qhi[r][cg * 16] = h8; *(bf16x8*)&Qlo[r][cg * 16] = l8;
#pragma unroll
        for (int j = 0; j < 8; ++j) { __bf16 hi, lo; split2(y[8 + j], hi, lo); h8[j] = hi; l8[j] = lo; }
        *(bf16x8*)&Qhi[r][cg * 16 + 8] = h8; *(bf16x8*)&Qlo[r][cg * 16 + 8] = l8;
      }
      // V (raw silu, f32)
      {
        float yv[8];
#pragma unroll
        for (int c = 0; c < 8; ++c) {
          const float4 w4 = *(const float4*)&cwv[cg * 8 + c][0];
          float v = w4.x * (float)vt4[0][c] + w4.y * (float)vt4[1][c] + w4.z * (float)vt4[2][c] + w4.w * (float)vt4[3][c];
          yv[c] = v * sigm(v);
        }
        f32x4 p0 = {yv[0], yv[1], yv[2], yv[3]};
        f32x4 p1 = {yv[4], yv[5], yv[6], yv[7]};
        *(f32x4*)&RHSb[r][cg * 8] = p0;
        *(f32x4*)&RHSb[r][cg * 8 + 4] = p1;
      }
      // decay scan + beta
      if (tid < 32) {
        float gv = g[gbase + t0 + tid];
        float bv = bet[gbase + t0 + tid];
        float cum = gv;
#pragma unroll
        for (int off = 1; off < 32; off <<= 1) {
          int src = (lane >= off) ? lane - off : lane;
          float n = __shfl(cum, src, 64);
          if (lane >= off) cum += n;
        }
        float LC = __shfl(cum, 31, 64);
        Lv[tid] = cum;
        Bv[tid] = bv;
        Bb2[tid] = __expf(cum);
        BCb[tid] = __expf(LC - cum);
      }
    }
    __syncthreads();   // B0

    // ================= stage 1: A,P from raw K,Q; folds ivk/ivq ==============
    {
      const int tr = w >> 1, tc = w & 1;
      const int jj = tc * 16 + r16;
      f32x4 accA = {0.f, 0.f, 0.f, 0.f}, accP = {0.f, 0.f, 0.f, 0.f};
      if (tc <= tr) {
#pragma unroll
        for (int kb = 0; kb < 128; kb += 32) {
          bf16x8 bh_ = *(const bf16x8*)&Khi[jj][kb + g2 * 8];
          bf16x8 bl_ = *(const bf16x8*)&Klo[jj][kb + g2 * 8];
          bf16x8 ah = *(const bf16x8*)&Khi[tr * 16 + r16][kb + g2 * 8];
          bf16x8 al = *(const bf16x8*)&Klo[tr * 16 + r16][kb + g2 * 8];
          accA = mfma3(ah, al, bh_, bl_, accA);
          bf16x8 qh = *(const bf16x8*)&Qhi[tr * 16 + r16][kb + g2 * 8];
          bf16x8 ql = *(const bf16x8*)&Qlo[tr * 16 + r16][kb + g2 * 8];
          accP = mfma3(qh, ql, bh_, bl_, accP);
        }
      }
      const float Lj = Lv[jj], ikj = ivk[jj];
#pragma unroll
      for (int reg = 0; reg < 4; ++reg) {
        const int tt = tr * 16 + g2 * 4 + reg;
        const float ex = __expf(Lv[tt] - Lj);
        const float av = (jj < tt) ? Bv[tt] * ivk[tt] * ikj * ex * accA[reg] : 0.f;
        const float pv = (jj <= tt) ? ivq[tt] * ikj * ex * accP[reg] : 0.f;
        __bf16 hi, lo;
        split2(av, hi, lo); Ahi[tt][jj] = hi; Alo[tt][jj] = lo;
        if (tr == 1 && tc == 0) { Athi[jj][tt - 16] = hi; Atlo[jj][tt - 16] = lo; }
        split2(pv, hi, lo); Phi[tt][jj] = hi; Plo[tt][jj] = lo;
      }
    }
    __syncthreads();   // B1

    // ================= stage 2a: U = Kraw*S0 ; GT = (Bv*V - f*U)^T ===========
    {
      const int rb = w >> 1, cbs = (w & 1) * 2;
      f32x4 acc[2] = {{0.f, 0.f, 0.f, 0.f}, {0.f, 0.f, 0.f, 0.f}};
#pragma unroll
      for (int kb = 0; kb < 128; kb += 32) {
        bf16x8 ah = *(const bf16x8*)&Khi[rb * 16 + r16][kb + g2 * 8];
        bf16x8 al = *(const bf16x8*)&Klo[rb * 16 + r16][kb + g2 * 8];
#pragma unroll
        for (int ct = 0; ct < 2; ++ct) {
          bf16x8 sh = *(const bf16x8*)&SThi[(cbs + ct) * 16 + r16][kb + g2 * 8];
          bf16x8 sl = *(const bf16x8*)&STlo[(cbs + ct) * 16 + r16][kb + g2 * 8];
          acc[ct] = mfma3(ah, al, sh, sl, acc[ct]);
        }
      }
#pragma unroll
      for (int ct = 0; ct < 2; ++ct) {
        const int cc = (cbs + ct) * 16 + r16;
#pragma unroll
        for (int reg = 0; reg < 4; ++reg) {
          const int tt = rb * 16 + g2 * 4 + reg;
          const float f1 = Bv[tt];
          const float f2 = f1 * Bb2[tt] * ivk[tt];
          const float val = f1 * RHSb[tt][cc] - f2 * acc[ct][reg];
          __bf16 hi, lo; split2(val, hi, lo);
          GThi[cc][tt] = hi; GTlo[cc][tt] = lo;
        }
      }
    }
    // ---- T_I = (I+L)^{-1}, waves 0,1; wave0 appends T0^T, wave1 X=T1*A10 ----
    if (w < 2) {
      const int I = w, r0 = I * 16, s = I + 2;
      bf16x8 Lh_r = z8, Ll_r = z8, Lh_t = z8, Ll_t = z8;
      if (g2 < 2) {
        Lh_r = *(const bf16x8*)&Ahi[r0 + r16][r0 + g2 * 8];
        Ll_r = *(const bf16x8*)&Alo[r0 + r16][r0 + g2 * 8];
#pragma unroll
        for (int j = 0; j < 8; ++j) {
          Lh_t[j] = Ahi[r0 + g2 * 8 + j][r0 + r16];
          Ll_t[j] = Alo[r0 + g2 * 8 + j][r0 + r16];
        }
      }
      f32x4 acc = {0.f, 0.f, 0.f, 0.f};
      acc = mfma3(Lh_r, Ll_r, Lh_t, Ll_t, acc);                  // L2
#pragma unroll
      for (int reg = 0; reg < 4; ++reg) { __bf16 hi, lo; split2(acc[reg], hi, lo);
        Thi[s][g2 * 4 + reg][r16] = hi; Tlo[s][g2 * 4 + reg][r16] = lo; }
      bf16x8 L2h_r = z8, L2l_r = z8, L2h_t = z8, L2l_t = z8;
      if (g2 < 2) { L2h_r = *(const bf16x8*)&Thi[s][r16][g2 * 8]; L2l_r = *(const bf16x8*)&Tlo[s][r16][g2 * 8]; }
#pragma unroll
      for (int j = 0; j < 8; ++j) if (g2 < 2) { L2h_t[j] = Thi[s][g2 * 8 + j][r16]; L2l_t[j] = Tlo[s][g2 * 8 + j][r16]; }
      bf16x8 nLh = Lh_r, nLl = Ll_r;
#pragma unroll
      for (int j = 0; j < 8; ++j) { nLh[j] = -nLh[j]; nLl[j] = -nLl[j]; }
      f32x4 accR;
#pragma unroll
      for (int reg = 0; reg < 4; ++reg) {
        const int rr = g2 * 4 + reg;
        float lw = (float)Ahi[r0 + rr][r0 + r16] + (float)Alo[r0 + rr][r0 + r16];
        float l2w = (float)Thi[s][rr][r16] + (float)Tlo[s][rr][r16];
        accR[reg] = ((rr == r16) ? 1.f : 0.f) - lw + l2w;
      }
      accR = mfma3(nLh, nLl, L2h_t, L2l_t, accR);                // R1
#pragma unroll
      for (int reg = 0; reg < 4; ++reg) { __bf16 hi, lo; split2(accR[reg], hi, lo);
        Thi[I][g2 * 4 + reg][r16] = hi; Tlo[I][g2 * 4 + reg][r16] = lo; }
      f32x4 acc4 = {0.f, 0.f, 0.f, 0.f};
      acc4 = mfma3(L2h_r, L2l_r, L2h_t, L2l_t, acc4);            // L4
#pragma unroll
      for (int reg = 0; reg < 4; ++reg) { __bf16 hi, lo; split2(acc4[reg], hi, lo);
        Thi[s][g2 * 4 + reg][r16] = hi; Tlo[s][g2 * 4 + reg][r16] = lo; }
      bf16x8 R1h_r = z8, R1l_r = z8, L4h_t = z8, L4l_t = z8, L4h_r = z8, L4l_r = z8;
      if (g2 < 2) {
        R1h_r = *(const bf16x8*)&Thi[I][r16][g2 * 8]; R1l_r = *(const bf16x8*)&Tlo[I][r16][g2 * 8];
        L4h_r = *(const bf16x8*)&Thi[s][r16][g2 * 8]; L4l_r = *(const bf16x8*)&Tlo[s][r16][g2 * 8];
#pragma unroll
        for (int j = 0; j < 8; ++j) { L4h_t[j] = Thi[s][g2 * 8 + j][r16]; L4l_t[j] = Tlo[s][g2 * 8 + j][r16]; }
      }
      f32x4 accR2;
#pragma unroll
      for (int reg = 0; reg < 4; ++reg)
        accR2[reg] = (float)Thi[I][g2 * 4 + reg][r16] + (float)Tlo[I][g2 * 4 + reg][r16];
      accR2 = mfma3(R1h_r, R1l_r, L4h_t, L4l_t, accR2);          // R2
#pragma unroll
      for (int reg = 0; reg < 4; ++reg) { __bf16 hi, lo; split2(accR2[reg], hi, lo);
        Thi[I][g2 * 4 + reg][r16] = hi; Tlo[I][g2 * 4 + reg][r16] = lo; }
      f32x4 acc8 = {0.f, 0.f, 0.f, 0.f};
      acc8 = mfma3(L4h_r, L4l_r, L4h_t, L4l_t, acc8);            // L8
#pragma unroll
      for (int reg = 0; reg < 4; ++reg) { __bf16 hi, lo; split2(acc8[reg], hi, lo);
        Thi[s][g2 * 4 + reg][r16] = hi; Tlo[s][g2 * 4 + reg][r16] = lo; }
      bf16x8 R2h_r = z8, R2l_r = z8, L8h_t = z8, L8l_t = z8;
      if (g2 < 2) {
        R2h_r = *(const bf16x8*)&Thi[I][r16][g2 * 8]; R2l_r = *(const bf16x8*)&Tlo[I][r16][g2 * 8];
#pragma unroll
        for (int j = 0; j < 8; ++j) { L8h_t[j] = Thi[s][g2 * 8 + j][r16]; L8l_t[j] = Tlo[s][g2 * 8 + j][r16]; }
      }
      f32x4 accT;
#pragma unroll
      for (int reg = 0; reg < 4; ++reg)
        accT[reg] = (float)Thi[I][g2 * 4 + reg][r16] + (float)Tlo[I][g2 * 4 + reg][r16];
      accT = mfma3(R2h_r, R2l_r, L8h_t, L8l_t, accT);            // T
#pragma unroll
      for (int reg = 0; reg < 4; ++reg) { __bf16 hi, lo; split2(accT[reg], hi, lo);
        Thi[I][g2 * 4 + reg][r16] = hi; Tlo[I][g2 * 4 + reg][r16] = lo; }
      if (I == 0) {
        // T0^T -> slot 2 (lane holds T0[g2*4+reg][r16] = T0t[r16][g2*4+reg])
#pragma unroll
        for (int reg = 0; reg < 4; ++reg) { __bf16 hi, lo; split2(accT[reg], hi, lo);
          Thi[2][r16][g2 * 4 + reg] = hi; Tlo[2][r16][g2 * 4 + reg] = lo; }
      } else {
        // X = T1*A10 -> slot 3 (rows)
        bf16x8 t1h = z8, t1l = z8, ath = z8, atl = z8;
        if (g2 < 2) {
          t1h = *(const bf16x8*)&Thi[1][r16][g2 * 8]; t1l = *(const bf16x8*)&Tlo[1][r16][g2 * 8];
          ath = *(const bf16x8*)&Athi[r16][g2 * 8];   atl = *(const bf16x8*)&Atlo[r16][g2 * 8];
        }
        f32x4 xacc = {0.f, 0.f, 0.f, 0.f};
        xacc = mfma3(t1h, t1l, ath, atl, xacc);
#pragma unroll
        for (int reg = 0; reg < 4; ++reg) { __bf16 hi, lo; split2(xacc[reg], hi, lo);
          Thi[3][g2 * 4 + reg][r16] = hi; Tlo[3][g2 * 4 + reg][r16] = lo; }
      }
    }
    __syncthreads();   // B2

    // ================= phase beta: Mneg = -(X*T0^T) (wave 1) =================
    if (w == 1) {
      bf16x8 xh = z8, xl = z8, th = z8, tl = z8;
      if (g2 < 2) {
        xh = *(const bf16x8*)&Thi[3][r16][g2 * 8]; xl = *(const bf16x8*)&Tlo[3][r16][g2 * 8];
        th = *(const bf16x8*)&Thi[2][r16][g2 * 8]; tl = *(const bf16x8*)&Tlo[2][r16][g2 * 8];
      }
      f32x4 macc = {0.f, 0.f, 0.f, 0.f};
      macc = mfma3(xh, xl, th, tl, macc);
#pragma unroll
      for (int reg = 0; reg < 4; ++reg) { __bf16 hi, lo; split2(-macc[reg], hi, lo);
        Mhi[g2 * 4 + reg][r16] = hi; Mlo[g2 * 4 + reg][r16] = lo; }
    }
    __syncthreads();   // B3

    // ================= V' solve (parallel): V'0=T0*R0, V'1=T1*R1+Mneg*R0 =====
    {
      const int c0 = w * 16;
      bf16x8 t0h = z8, t0l = z8, g0h = z8, g0l = z8, t1h = z8, t1l = z8;
      bf16x8 g1h = z8, g1l = z8, mh = z8, ml = z8;
      if (g2 < 2) {
        t0h = *(const bf16x8*)&Thi[0][r16][g2 * 8]; t0l = *(const bf16x8*)&Tlo[0][r16][g2 * 8];
        t1h = *(const bf16x8*)&Thi[1][r16][g2 * 8]; t1l = *(const bf16x8*)&Tlo[1][r16][g2 * 8];
        mh  = *(const bf16x8*)&Mhi[r16][g2 * 8];    ml  = *(const bf16x8*)&Mlo[r16][g2 * 8];
        g0h = *(const bf16x8*)&GThi[c0 + r16][g2 * 8];      g0l = *(const bf16x8*)&GTlo[c0 + r16][g2 * 8];
        g1h = *(const bf16x8*)&GThi[c0 + r16][16 + g2 * 8]; g1l = *(const bf16x8*)&GTlo[c0 + r16][16 + g2 * 8];
      }
      f32x4 a0 = {0.f, 0.f, 0.f, 0.f}, a1 = {0.f, 0.f, 0.f, 0.f};
      a0 = mfma3(t0h, t0l, g0h, g0l, a0);
      a1 = mfma3(t1h, t1l, g1h, g1l, a1);
      a1 = mfma3(mh, ml, g0h, g0l, a1);
      bf16x4 vh, vl, v2h, v2l;
#pragma unroll
      for (int reg = 0; reg < 4; ++reg) {
        const int ti = g2 * 4 + reg;
        __bf16 hi, lo; split2(a0[reg], hi, lo); vh[reg] = hi; vl[reg] = lo;
        split2(a0[reg] * BCb[ti] * ivk[ti], hi, lo); v2h[reg] = hi; v2l[reg] = lo;
      }
      *(bf16x4*)&VThi[c0 + r16][g2 * 4] = vh;  *(bf16x4*)&VTlo[c0 + r16][g2 * 4] = vl;
      *(bf16x4*)&V2hi[c0 + r16][g2 * 4] = v2h; *(bf16x4*)&V2lo[c0 + r16][g2 * 4] = v2l;
#pragma unroll
      for (int reg = 0; reg < 4; ++reg) {
        const int ti = 16 + g2 * 4 + reg;
        __bf16 hi, lo; split2(a1[reg], hi, lo); vh[reg] = hi; vl[reg] = lo;
        split2(a1[reg] * BCb[ti] * ivk[ti], hi, lo); v2h[reg] = hi; v2l[reg] = lo;
      }
      *(bf16x4*)&VThi[c0 + r16][16 + g2 * 4] = vh;  *(bf16x4*)&VTlo[c0 + r16][16 + g2 * 4] = vl;
      *(bf16x4*)&V2hi[c0 + r16][16 + g2 * 4] = v2h; *(bf16x4*)&V2lo[c0 + r16][16 + g2 * 4] = v2l;
    }
    __syncthreads();   // B4

    // ================= stage 3a: O = rowscale(Qraw*S0) + P*V' ================
    {
      const int rb = w >> 1, cbs = (w & 1) * 2;
      f32x4 acc[2] = {{0.f, 0.f, 0.f, 0.f}, {0.f, 0.f, 0.f, 0.f}};
#pragma unroll
      for (int kb = 0; kb < 128; kb += 32) {
        bf16x8 qh = *(const bf16x8*)&Qhi[rb * 16 + r16][kb + g2 * 8];
        bf16x8 ql = *(const bf16x8*)&Qlo[rb * 16 + r16][kb + g2 * 8];
#pragma unroll
        for (int ct = 0; ct < 2; ++ct) {
          bf16x8 sh = *(const bf16x8*)&SThi[(cbs + ct) * 16 + r16][kb + g2 * 8];
          bf16x8 sl = *(const bf16x8*)&STlo[(cbs + ct) * 16 + r16][kb + g2 * 8];
          acc[ct] = mfma3(qh, ql, sh, sl, acc[ct]);
        }
      }
      float fr[4];
#pragma unroll
      for (int reg = 0; reg < 4; ++reg) { const int tt = rb * 16 + g2 * 4 + reg; fr[reg] = Bb2[tt] * ivq[tt]; }
#pragma unroll
      for (int ct = 0; ct < 2; ++ct)
#pragma unroll
        for (int reg = 0; reg < 4; ++reg) acc[ct][reg] *= fr[reg];
      bf16x8 ph = *(const bf16x8*)&Phi[rb * 16 + r16][g2 * 8];
      bf16x8 pl = *(const bf16x8*)&Plo[rb * 16 + r16][g2 * 8];
#pragma unroll
      for (int ct = 0; ct < 2; ++ct) {
        bf16x8 vh = *(const bf16x8*)&VThi[(cbs + ct) * 16 + r16][g2 * 8];
        bf16x8 vl = *(const bf16x8*)&VTlo[(cbs + ct) * 16 + r16][g2 * 8];
        acc[ct] = mfma3(ph, pl, vh, vl, acc[ct]);
        const int cc = (cbs + ct) * 16 + r16;
#pragma unroll
        for (int reg = 0; reg < 4; ++reg)
          o[obase + (size_t)(t0 + rb * 16 + g2 * 4 + reg) * DVd + cc] = (__bf16)acc[ct][reg];
      }
    }
    __syncthreads();   // B5

    // ================= stage 3b: S = bC*S0 + Kraw^T * V'2 ====================
    {
      const float bCf = Bb2[31];
      bf16x8 v2h4[4], v2l4[4];
#pragma unroll
      for (int cb = 0; cb < 4; ++cb) {
        v2h4[cb] = *(const bf16x8*)&V2hi[cb * 16 + r16][g2 * 8];
        v2l4[cb] = *(const bf16x8*)&V2lo[cb * 16 + r16][g2 * 8];
      }
#pragma unroll
      for (int rr = 0; rr < 2; ++rr) {
        const int d0 = (w * 2 + rr) * 16;
        bf16x8 kh, kl;
#pragma unroll
        for (int j = 0; j < 8; ++j) {
          const int t = g2 * 8 + j;
          kh[j] = Khi[t][d0 + r16]; kl[j] = Klo[t][d0 + r16];
        }
#pragma unroll
        for (int cb = 0; cb < 4; ++cb) {
          const int cc = cb * 16 + r16;
          f32x4 acc;
#pragma unroll
          for (int reg = 0; reg < 4; ++reg) {
            const int dd = d0 + g2 * 4 + reg;
            acc[reg] = bCf * ((float)SThi[cc][dd] + (float)STlo[cc][dd]);
          }
          acc = mfma3(kh, kl, v2h4[cb], v2l4[cb], acc);
          bf16x4 p4h, p4l;
#pragma unroll
          for (int reg = 0; reg < 4; ++reg) { __bf16 hi, lo; split2(acc[reg], hi, lo); p4h[reg] = hi; p4l[reg] = lo; }
          *(bf16x4*)&SThi[cc][d0 + g2 * 4] = p4h;
          *(bf16x4*)&STlo[cc][d0 + g2 * 4] = p4l;
        }
      }
    }
    __syncthreads();   // B6 (end of chunk)
  }
}

// ---------------- gated RMSNorm epilogue + split-bf16 of o ----------------
__global__ void epilogue_kernel(const __bf16* __restrict__ o, const __bf16* __restrict__ gate,
                                const float* __restrict__ wn, __bf16* __restrict__ Os)
{
  const int bid = blockIdx.x;          // m*H + h
  const int m = bid / HH, h = bid - m * HH;
  const int b = m >> 11, t = m & (TT - 1);
  const int j = threadIdx.x;
  const float ov = (float)o[((size_t)(b * HH + h) * TT + t) * DVd + j];
  float ss = ov * ov;
#pragma unroll
  for (int off = 32; off; off >>= 1) ss += __shfl_xor(ss, off, 64);
  __shared__ float red[4];
  if ((j & 63) == 0) red[j >> 6] = ss;
  __syncthreads();
  const float inv = rsqrtf((red[0] + red[1] + red[2] + red[3]) * (1.f / DVd) + 1e-5f);
  const float gt = (float)gate[(size_t)m * K2 + h * DVd + j];
  const float val = ov * inv * wn[j] * (gt * sigm(gt));
  const __bf16 hi = (__bf16)val;
  const __bf16 lo = (__bf16)(val - (float)hi);
  const size_t ob = (size_t)m * (2 * K2) + h * DVd + j;
  Os[ob] = hi; Os[ob + K2] = lo;
}

// ---------------- ws-too-small sentinel ----------------
__global__ void sentinel_kernel(float* __restrict__ out, float val) {
  out[threadIdx.x] = val;
}

// ---------------- launch ----------------
extern "C" void kernel_launch(void* const* d_in, const int* in_sizes, int n_in,
                              void* d_out, int out_size, void* d_ws, size_t ws_size,
                              hipStream_t stream) {
  const float* x    = (const float*)d_in[0];
  const float* Wq   = (const float*)d_in[1];
  const float* Wk   = (const float*)d_in[2];
  const float* Wv   = (const float*)d_in[3];
  const float* Wa   = (const float*)d_in[4];
  const float* Wb   = (const float*)d_in[5];
  const float* Wg   = (const float*)d_in[6];
  const float* Wo   = (const float*)d_in[7];
  const float* cq   = (const float*)d_in[8];
  const float* ck   = (const float*)d_in[9];
  const float* cv   = (const float*)d_in[10];
  const float* Alog = (const float*)d_in[11];
  const float* dtb  = (const float*)d_in[12];
  const float* onw  = (const float*)d_in[13];
  float* out = (float*)d_out;
  uint8_t* ws = (uint8_t*)d_ws;

  // ---- workspace layout (bytes); lifetime-aliased. peak = 230,424,576 ----
  const size_t oGt = 0;                    // gate bf16 [16384,1536]   50,331,648
  const size_t oG  = oGt + 50331648;       // g f32 [48,2048]             393,216
  const size_t oBt = oG  + 393216;         // beta f32                    393,216
  const size_t oWo = oBt + 393216;         // Wo' bf16 [768,4608]       7,077,888
  const size_t oWq = oWo + 7077888;        // Wq' bf16 [768,2304]       3,538,944
  const size_t oWk = oWq + 3538944;
  const size_t oWv = oWk + 3538944;        // Wv' bf16 [1536,2304]      7,077,888
  const size_t oWg = oWv + 7077888;
  const size_t oXs = oWg + 7077888;        // Xs bf16 [16384,1536]     50,331,648
  const size_t oQp = oXs + 50331648;       // qpre bf16 [16384,768]    25,165,824
  const size_t oKp = oQp + 25165824;
  const size_t oVp = oKp + 25165824;       // vpre bf16 [16384,1536]   50,331,648
  const size_t total = oVp + 50331648;     // 230,424,576
  const size_t oO  = oXs;                  // o bf16 over Xs (dead after GEMMs)
  const size_t oOs = oQp;                  // Os bf16 over pre bufs (dead after delta)

  if (ws_size < total) {
    sentinel_kernel<<<1, 256, 0, stream>>>(out, 1.0e7f + (float)(ws_size >> 20));
    return;
  }

  __bf16* Xs   = (__bf16*)(ws + oXs);
  __bf16* Wqp  = (__bf16*)(ws + oWq);
  __bf16* Wkp  = (__bf16*)(ws + oWk);
  __bf16* Wvp  = (__bf16*)(ws + oWv);
  __bf16* Wgp  = (__bf16*)(ws + oWg);
  __bf16* Wop  = (__bf16*)(ws + oWo);
  __bf16* qpre = (__bf16*)(ws + oQp);
  __bf16* kpre = (__bf16*)(ws + oKp);
  __bf16* vpre = (__bf16*)(ws + oVp);
  __bf16* gate = (__bf16*)(ws + oGt);
  float*  gbuf = (float*)(ws + oG);
  float*  bbuf = (float*)(ws + oBt);
  __bf16* oBuf = (__bf16*)(ws + oO);
  __bf16* Os   = (__bf16*)(ws + oOs);

  // phase A: conversions + projections
  convert_x_kernel<<<MM * DD / 256, 256, 0, stream>>>(x, Xs);
  convert_w_kernel<<<768 * 3 * K1 / 256, 256, 0, stream>>>(Wq, Wqp, K1, 768);
  convert_w_kernel<<<768 * 3 * K1 / 256, 256, 0, stream>>>(Wk, Wkp, K1, 768);
  convert_w_kernel<<<1536 * 3 * K1 / 256, 256, 0, stream>>>(Wv, Wvp, K1, 1536);
  convert_w_kernel<<<1536 * 3 * K1 / 256, 256, 0, stream>>>(Wg, Wgp, K1, 1536);
  convert_w_kernel<<<768 * 3 * K2 / 256, 256, 0, stream>>>(Wo, Wop, K2, 768);
  gemm_split<__bf16><<<dim3(128, 6),  256, 0, stream>>>(Xs, Wqp, qpre, 768,  K1);
  gemm_split<__bf16><<<dim3(128, 6),  256, 0, stream>>>(Xs, Wkp, kpre, 768,  K1);
  gemm_split<__bf16><<<dim3(128, 12), 256, 0, stream>>>(Xs, Wvp, vpre, 1536, K1);
  gemm_split<__bf16><<<dim3(128, 12), 256, 0, stream>>>(Xs, Wgp, gate, 1536, K1);
  gb_kernel<<<MM / 4, 256, 0, stream>>>(x, Wa, Wb, Alog, dtb, gbuf, bbuf);
  // phase C: chunked gated delta rule (conv/silu/l2norm fused)
  delta_kernel<<<dim3(BB * HH, 4), 256, 0, stream>>>(qpre, kpre, vpre, cq, ck, cv,
                                                     gbuf, bbuf, oBuf);
  // phase D: gated RMSNorm + split-bf16, final projection
  epilogue_kernel<<<MM * HH, 256, 0, stream>>>(oBuf, gate, onw, Os);
  gemm_split<float><<<dim3(128, 6), 256, 0, stream>>>(Os, Wop, out, 768, K2);
}